// Round 2
// baseline (216.675 us; speedup 1.0000x reference)
//
#include <hip/hip_runtime.h>

#define NPOLE 160
#define KDIM  640
#define TDIM  10
#define PDIM  2048
#define BDIM  2
#define NJ    4096            // BDIM*PDIM
#define MAXIT 100
#define NBJ   64              // j-tiles of 64 (one wave-width)
#define NTHR  256
#define KPW   160             // k per wave (KDIM/4)

// ws float offsets
// floats: [0]linv [1]lambd [2]tt [3]done [4]t [5]r
// ints at ws+32: [0]oscF [1]oscS [2]kpos [3]gap [4]parity [8+ii]tickets(100)
#define OFF_I    32
#define OFF_D    160          // 6400  (layout [t][k])
#define OFF_ROWL 6560         // 640
#define OFF_VKB  7200         // 100
#define OFF_VKP  7312         // 64
#define OFF_CVP  7376         // 64
#define OFF_U0   7440         // 40960
#define OFF_U1   48400        // 40960
#define OFF_XB   89600        // 2621440
#define WS_FLOATS (OFF_XB + BDIM*KDIM*PDIM)   // 2,711,040 floats = 10.85 MB

__device__ __forceinline__ float sgnf(float x) {
  return (x > 0.f) ? 1.f : ((x < 0.f) ? -1.f : 0.f);
}

__global__ void k_build(const float* __restrict__ Drr, const float* __restrict__ Dth,
                        float* __restrict__ ws) {
  if (blockIdx.x == 0) {  // zero int state + tickets every call (graph replays!)
    int* wsI = (int*)(ws + OFF_I);
    for (int i = threadIdx.x; i < 128; i += 64) wsI[i] = 0;
  }
  int k = blockIdx.x * 64 + threadIdx.x;
  if (k >= KDIM) return;
  int n = k % NPOLE, grp = k / NPOLE;
  float r = Drr[n], th = Dth[n];
  float col[TDIM]; float ss = 0.f; float ri = 1.f;
  #pragma unroll
  for (int i = 0; i < TDIM; ++i) {
    float ang = (float)i * th;
    float c = cosf(ang), s = sinf(ang);
    float sgn = (i & 1) ? -1.f : 1.f;
    float v;
    if (grp == 0) v = ri * c;
    else if (grp == 1) v = sgn * ri * c;
    else if (grp == 2) v = ri * s;
    else v = sgn * ri * s;
    col[i] = v; ss += v * v;
    ri *= r;
  }
  float G = sqrtf(ss);
  if (G == 0.f) G = sqrtf((float)TDIM);
  #pragma unroll
  for (int i = 0; i < TDIM; ++i) ws[OFF_D + i * KDIM + k] = col[i] / G;
}

__global__ void k_rowL(float* __restrict__ ws) {
  int k = blockIdx.x;
  int lane = threadIdx.x;  // 64
  float dk[TDIM];
  #pragma unroll
  for (int t = 0; t < TDIM; ++t) dk[t] = ws[OFF_D + t * KDIM + k];
  float acc = 0.f;
  for (int kk = lane; kk < KDIM; kk += 64) {
    float dot = 0.f;
    #pragma unroll
    for (int t = 0; t < TDIM; ++t) dot += dk[t] * ws[OFF_D + t * KDIM + kk];
    acc += dot * dot;
  }
  #pragma unroll
  for (int o = 32; o > 0; o >>= 1) acc += __shfl_down(acc, o);
  if (lane == 0) ws[OFF_ROWL + k] = acc;
}

__global__ void k_fin(float* __restrict__ ws) {
  int lane = threadIdx.x;  // 64
  float acc = 0.f;
  for (int k = lane; k < KDIM; k += 64) acc += ws[OFF_ROWL + k];
  #pragma unroll
  for (int o = 32; o > 0; o >>= 1) acc += __shfl_down(acc, o);
  if (lane == 0) {
    float L = sqrtf(acc);
    ws[0] = 1.f / L;          // linv
    ws[1] = 0.1f / L;         // lambd
  }
}

// One FISTA iteration. Each block owns 64 j's (all k); waves split k.
// Last block (atomic ticket) performs the scalar/control update.
__global__ void __launch_bounds__(NTHR)
k_iter(const float* __restrict__ Y, float* __restrict__ ws,
       float* __restrict__ out, int ii) {
  const int tid = threadIdx.x, bj = blockIdx.x;
  const int w = tid >> 6, l = tid & 63;
  const int j = (bj << 6) | l;
  const int b = j >> 11, p = j & (PDIM - 1);
  int* wsI = (int*)(ws + OFF_I);

  const int c0 = (ii == 0), pz = (ii <= 1);
  if (!c0 && ws[3] != 0.f) return;          // done flag from previous launch
  const float tt = c0 ? 0.f : ws[2];
  const float om = 1.f + tt;
  const float linv = ws[0], lambd = ws[1];

  // x ping-pong: buf0 = out, buf1 = ws. x_new@ii -> buf[ii&1] (in-place over x_old).
  float* bufO = out;
  float* bufW = ws + OFF_XB;
  float*       xnw  = (ii & 1) ? bufW : bufO;   // holds x_old, overwritten by x_new
  const float* xcur = (ii & 1) ? bufO : bufW;   // x entering this iteration
  // u ping-pong, same parity rule
  const float* uc = ws + ((ii & 1) ? OFF_U0 : OFF_U1);  // D@x_cur
  const float* up = ws + ((ii & 1) ? OFF_U1 : OFF_U0);  // D@x_old
  float*       un = ws + ((ii & 1) ? OFF_U1 : OFF_U0);  // D@x_new (overwrites up)

  __shared__ float Dl[KDIM][TDIM];       // 25.6 KB
  __shared__ float znL[4][TDIM][64];     // 10 KB
  __shared__ float red[NTHR], red2[NTHR];
  __shared__ float csum[KDIM];
  __shared__ double Mm[TDIM][TDIM];
  __shared__ int lastFlag;
  __shared__ float bcast[2];

  for (int i = tid; i < TDIM * KDIM; i += NTHR) {
    int t = i / KDIM, k = i - t * KDIM;
    Dl[k][t] = ws[OFF_D + i];
  }

  float zj[TDIM], Yreg[TDIM];
  #pragma unroll
  for (int t = 0; t < TDIM; ++t) {
    Yreg[t] = Y[(b * TDIM + t) * PDIM + p];
    if (c0) zj[t] = 0.f;
    else {
      float a  = uc[t * NJ + j];
      float bb = pz ? 0.f : up[t * NJ + j];
      zj[t] = om * a - tt * bb;            // (D @ y)[t,j]
    }
  }
  __syncthreads();

  float zn[TDIM];
  #pragma unroll
  for (int t = 0; t < TDIM; ++t) zn[t] = 0.f;
  float vk = 0.f, cv = 0.f;
  const int kbase = w * KPW;

  for (int s = 0; s < KPW; ++s) {
    int k = kbase + s;
    int addr = ((b * KDIM + k) << 11) | p;
    float xcv = c0 ? 0.f : xcur[addr];
    float xov = pz ? 0.f : xnw[addr];
    float y   = c0 ? 0.f : om * xcv - tt * xov;
    float wd = 0.f, dt = 0.f;
    #pragma unroll
    for (int t = 0; t < TDIM; ++t) { wd += Dl[k][t] * zj[t]; dt += Dl[k][t] * Yreg[t]; }
    float v = y + linv * (dt - wd);        // y - linv*(DtD y)[k] + linv*(DtY)[k]
    float xv = (v > lambd) ? v - lambd : ((v < -lambd) ? v + lambd : 0.f);
    xnw[addr] = xv;
    #pragma unroll
    for (int t = 0; t < TDIM; ++t) zn[t] += Dl[k][t] * xv;
    vk += (y - xv) * (xv - xcv);
    float d = xv - xcv; cv += d * d;
  }

  #pragma unroll
  for (int t = 0; t < TDIM; ++t) znL[w][t][l] = zn[t];
  red[tid] = vk; red2[tid] = cv;
  __syncthreads();
  if (tid < TDIM * 64) {                   // u_new for this block's j's
    int t = tid >> 6, l2 = tid & 63;
    float s = znL[0][t][l2] + znL[1][t][l2] + znL[2][t][l2] + znL[3][t][l2];
    un[t * NJ + ((bj << 6) | l2)] = s;
  }
  for (int o = NTHR >> 1; o > 0; o >>= 1) {
    if (tid < o) { red[tid] += red[tid + o]; red2[tid] += red2[tid + o]; }
    __syncthreads();
  }
  if (tid == 0) {
    ws[OFF_VKP + bj] = red[0];
    ws[OFF_CVP + bj] = red2[0];
    __threadfence();
    int old = atomicAdd(&wsI[8 + ii], 1);
    lastFlag = (old == NBJ - 1);
  }
  __syncthreads();
  if (!lastFlag) return;
  __threadfence();                          // acquire: see all blocks' writes

  // ---------------- scalar / control update (last block only) ----------------
  if (tid < 64) {
    float va = ws[OFF_VKP + tid], ca = ws[OFF_CVP + tid];
    #pragma unroll
    for (int o = 32; o > 0; o >>= 1) { va += __shfl_down(va, o); ca += __shfl_down(ca, o); }
    if (tid == 0) { bcast[0] = va; bcast[1] = ca; }
  }
  __syncthreads();
  const float vkt = bcast[0], cvt = bcast[1];

  float st_t = c0 ? 1.f : ws[4];
  float st_r = c0 ? 4.f : ws[5];
  int oscF = c0 ? 1 : wsI[0];
  int oscS = c0 ? 0 : wsI[1];
  int kpos = c0 ? 0 : wsI[2];
  int gap  = c0 ? 0 : wsI[3];

  int cond1 = oscF && (vkt >= 0.f);
  int Lg = ii - kpos;
  float sum_k = 0.f;
  if (Lg >= 3) {
    int i1 = ii - 1;   i1 = i1 < 0 ? 0 : (i1 > MAXIT - 1 ? MAXIT - 1 : i1);
    int i2 = kpos + 1; i2 = i2 < 0 ? 0 : (i2 > MAXIT - 1 ? MAXIT - 1 : i2);
    sum_k = sgnf(ws[OFF_VKB + i1]) - sgnf(ws[OFF_VKB + i2]);
  }
  int cond2 = oscS && (vkt <= 0.f) && (Lg >= 2 * gap) && (sum_k == 0.f);

  float r_alpha = 0.f;
  if (cond1 || cond2) {
    // column sums of x_new over (b,p): wave w handles k = w, w+4, ...
    for (int k = w; k < KDIM; k += 4) {
      float acc = 0.f;
      for (int idx = l; idx < NJ; idx += 64) {
        int b2 = idx >> 11, p2 = idx & (PDIM - 1);
        acc += xnw[((b2 * KDIM + k) << 11) | p2];
      }
      #pragma unroll
      for (int o = 32; o > 0; o >>= 1) acc += __shfl_down(acc, o);
      if (l == 0) csum[k] = acc;
    }
    __syncthreads();
    // masked 10x10 Gram (same nonzero spectrum as masked 640x640 DtD)
    float accE = 0.f;
    if (tid < 55) {
      int cnt = tid, ea = 0, eb = 0;
      for (int q = 0; q < TDIM; ++q) { int row = TDIM - q; if (cnt < row) { ea = q; eb = q + cnt; break; } cnt -= row; }
      for (int k = 0; k < KDIM; ++k) {
        float m = fabsf(csum[k] / (float)PDIM / (float)BDIM);
        if (m >= 1e-3f) accE += Dl[k][ea] * Dl[k][eb];
      }
    }
    if (w == 0) {
      for (int e2 = 0; e2 < 55; ++e2) {
        float vsh = __shfl(accE, e2);
        if (l == 0) {
          int cnt = e2, a2 = 0, b2 = 0;
          for (int q = 0; q < TDIM; ++q) { int row = TDIM - q; if (cnt < row) { a2 = q; b2 = q + cnt; break; } cnt -= row; }
          Mm[a2][b2] = (double)vsh; Mm[b2][a2] = (double)vsh;
        }
      }
    }
    __syncthreads();
    if (tid == 0) {
      for (int sw = 0; sw < 60; ++sw) {
        double off = 0.0;
        for (int a2 = 0; a2 < TDIM; ++a2)
          for (int b2 = a2 + 1; b2 < TDIM; ++b2) off += Mm[a2][b2] * Mm[a2][b2];
        if (off < 1e-22) break;
        for (int a2 = 0; a2 < TDIM - 1; ++a2)
          for (int b2 = a2 + 1; b2 < TDIM; ++b2) {
            double apq = Mm[a2][b2];
            if (fabs(apq) < 1e-30) continue;
            double app = Mm[a2][a2], aqq = Mm[b2][b2];
            double theta = (aqq - app) / (2.0 * apq);
            double tj = (theta >= 0.0 ? 1.0 : -1.0) / (fabs(theta) + sqrt(theta * theta + 1.0));
            double cj = 1.0 / sqrt(tj * tj + 1.0);
            double sj = tj * cj;
            for (int q2 = 0; q2 < TDIM; ++q2) {
              double ap = Mm[a2][q2], aq = Mm[b2][q2];
              Mm[a2][q2] = cj * ap - sj * aq;
              Mm[b2][q2] = sj * ap + cj * aq;
            }
            for (int q2 = 0; q2 < TDIM; ++q2) {
              double ap = Mm[q2][a2], aq = Mm[q2][b2];
              Mm[q2][a2] = cj * ap - sj * aq;
              Mm[q2][b2] = sj * ap + cj * aq;
            }
          }
      }
      float pmin = 3.4e38f; int found = 0;
      for (int a2 = 0; a2 < TDIM; ++a2) {
        float ev = (float)Mm[a2][a2];
        if (ev > 1e-4f) { if (ev < pmin) pmin = ev; found = 1; }
      }
      float pp = found ? pmin : 1.0f;
      float sq = sqrtf(linv * pp);
      bcast[0] = 4.0f * (1.0f - sq) * (1.0f - sq) / (1.0f - pp * linv);
    }
    __syncthreads();
    r_alpha = bcast[0];
  }

  float r1 = (r_alpha == 4.0f) ? 3.99f : r_alpha;
  float r_new = cond1 ? r1 : (cond2 ? r_alpha : st_r);
  float t_cur = cond1 ? (4.0f / (4.0f - r1) / 1.1f) : st_t;
  int kpos_n = cond1 ? (ii + 10) : kpos;
  int gap_n  = cond1 ? ii : gap;
  int oscF_n = oscF && !cond1;
  int oscS_n = cond1 ? 1 : (oscS && !cond2);
  float t_next = (1.f + sqrtf(1.f + r_new * t_cur * t_cur)) * 0.5f;
  float tt_new = (t_cur - 1.f) / t_next;
  float conv = sqrtf(cvt) / (c0 ? (float)PDIM : (float)KDIM);
  if (tid == 0) {
    ws[OFF_VKB + ii] = vkt;
    ws[2] = tt_new;
    ws[3] = (conv < 0.01f) ? 1.f : 0.f;
    ws[4] = t_next; ws[5] = r_new;
    wsI[0] = oscF_n; wsI[1] = oscS_n; wsI[2] = kpos_n; wsI[3] = gap_n;
    wsI[4] = ii & 1;                       // parity of the final-x buffer
  }
}

__global__ void k_final(float* __restrict__ ws, float* __restrict__ out) {
  int* wsI = (int*)(ws + OFF_I);
  if (wsI[4] == 0) return;                 // final x already in out
  const float* src = ws + OFF_XB;
  const int n = BDIM * KDIM * PDIM;
  for (int i = blockIdx.x * blockDim.x + threadIdx.x; i < n; i += gridDim.x * blockDim.x)
    out[i] = src[i];
}

extern "C" void kernel_launch(void* const* d_in, const int* in_sizes, int n_in,
                              void* d_out, int out_size, void* d_ws, size_t ws_size,
                              hipStream_t stream) {
  (void)in_sizes; (void)n_in; (void)out_size;
  if (ws_size < (size_t)WS_FLOATS * 4) return;
  const float* Y   = (const float*)d_in[0];
  const float* Drr = (const float*)d_in[1];
  const float* Dth = (const float*)d_in[2];
  float* out = (float*)d_out;
  float* ws  = (float*)d_ws;

  hipLaunchKernelGGL(k_build, dim3(10), dim3(64), 0, stream, Drr, Dth, ws);
  hipLaunchKernelGGL(k_rowL, dim3(KDIM), dim3(64), 0, stream, ws);
  hipLaunchKernelGGL(k_fin, dim3(1), dim3(64), 0, stream, ws);
  for (int ii = 0; ii < MAXIT; ++ii)
    hipLaunchKernelGGL(k_iter, dim3(NBJ), dim3(NTHR), 0, stream, Y, ws, out, ii);
  hipLaunchKernelGGL(k_final, dim3(256), dim3(NTHR), 0, stream, ws, out);
}

// Round 4
// 78.407 us; speedup vs baseline: 2.7635x; 2.7635x over previous
//
#include <hip/hip_runtime.h>

#define NPOLE 160
#define KDIM  640
#define TDIM  10
#define PDIM  2048
#define BDIM  2
#define NJ    4096            // BDIM*PDIM
#define MAXIT 100
#define NBLK  256             // j-tiles of 16 columns each
#define NTHR  256
#define JPB   16              // j per block
#define KCH   16              // k-chunks per block (one per thread group of 16)
#define KPT   40              // k per thread

// ws float offsets
#define OFF_BAR  0            // 16 floats (memset 64 B each launch): [0]=barrier counter
#define OFF_SC   16           // [0]=tt [1]=done
#define OFF_VKP  64           // 256
#define OFF_CVP  320          // 256
#define OFF_XB   576          // 2621440 (x ping-pong partner of d_out)
#define WS_FLOATS (OFF_XB + BDIM*KDIM*PDIM)   // 2,622,016 floats = 10.49 MB

__device__ __forceinline__ float sgnf(float x) {
  return (x > 0.f) ? 1.f : ((x < 0.f) ? -1.f : 0.f);
}

// software grid barrier: one monotonic counter, zeroed by hipMemsetAsync per launch.
// Co-residency guaranteed: 256 blocks, >=3 blocks/CU capacity on 256 CUs.
__device__ __forceinline__ void gbar(int* ctr, int target) {
  __syncthreads();
  if (threadIdx.x == 0) {
    __threadfence();   // release this block's global writes to device scope
    (void)__hip_atomic_fetch_add(ctr, 1, __ATOMIC_ACQ_REL, __HIP_MEMORY_SCOPE_AGENT);
    int guard = 0;
    while (__hip_atomic_load(ctr, __ATOMIC_ACQUIRE, __HIP_MEMORY_SCOPE_AGENT) < target) {
      __builtin_amdgcn_s_sleep(1);
      if (++guard > (1 << 26)) break;   // bail-out: never hang the harness
    }
  }
  __syncthreads();
}

__global__ void __launch_bounds__(NTHR)
k_persist(const float* __restrict__ Y, const float* __restrict__ Drr,
          const float* __restrict__ Dth, float* __restrict__ ws,
          float* __restrict__ out)
{
  const int tid = threadIdx.x, blk = blockIdx.x;
  const int w = tid >> 6, l = tid & 63;
  const int jl = tid & 15;            // j within tile
  const int kc = tid >> 4;            // k-chunk 0..15
  const int j = blk * JPB + jl;
  const int b = j >> 11, p = j & (PDIM - 1);
  const int k0 = kc * KPT;
  int* bar = (int*)(ws + OFF_BAR);

  __shared__ float Dl[KDIM][TDIM];        // 25.6 KB
  __shared__ float znL[KCH][TDIM][JPB];   // 10.2 KB
  __shared__ float uL[2][TDIM][JPB];      // 1.3 KB  (block-private u = D@x)
  __shared__ float red[NTHR], red2[NTHR];
  __shared__ float csum[KDIM];
  __shared__ float Msh[64];
  __shared__ double Mm[TDIM][TDIM];
  __shared__ float vkbufL[MAXIT];
  __shared__ float bc[2];

  // ---- build normalized dictionary into LDS (redundant per block) ----
  for (int k = tid; k < KDIM; k += NTHR) {
    int n = k % NPOLE, grp = k / NPOLE;
    float r = Drr[n], th = Dth[n];
    float col[TDIM]; float ss = 0.f, ri = 1.f;
    #pragma unroll
    for (int i = 0; i < TDIM; ++i) {
      float ang = (float)i * th;
      float c = cosf(ang), s = sinf(ang);
      float sgn = (i & 1) ? -1.f : 1.f;
      float v = (grp == 0) ? ri * c : (grp == 1) ? sgn * ri * c
               : (grp == 2) ? ri * s : sgn * ri * s;
      col[i] = v; ss += v * v; ri *= r;
    }
    float G = sqrtf(ss); if (G == 0.f) G = sqrtf((float)TDIM);
    float gi = 1.f / G;
    #pragma unroll
    for (int i = 0; i < TDIM; ++i) Dl[k][i] = col[i] * gi;
  }
  __syncthreads();

  // ---- L = ||DtD||_F via 10x10 D·D^T Frobenius identity (redundant) ----
  for (int e = w; e < 55; e += 4) {
    int cnt = e, t1 = 0, t2 = 0;
    for (int q = 0; q < TDIM; ++q) { int row = TDIM - q; if (cnt < row) { t1 = q; t2 = q + cnt; break; } cnt -= row; }
    float acc = 0.f;
    for (int k = l; k < KDIM; k += 64) acc += Dl[k][t1] * Dl[k][t2];
    #pragma unroll
    for (int o = 32; o > 0; o >>= 1) acc += __shfl_down(acc, o);
    if (l == 0) Msh[e] = acc;
  }
  __syncthreads();
  float fro = 0.f;
  {
    int e = 0;
    for (int t1 = 0; t1 < TDIM; ++t1)
      for (int t2 = t1; t2 < TDIM; ++t2, ++e) {
        float m = Msh[e];
        fro += (t1 == t2 ? 1.f : 2.f) * m * m;
      }
  }
  const float linv = 1.f / sqrtf(fro);
  const float lambd = 0.1f * linv;

  float Yreg[TDIM];
  #pragma unroll
  for (int t = 0; t < TDIM; ++t) Yreg[t] = Y[(b * TDIM + t) * PDIM + p];

  float* wsX = ws + OFF_XB;

  float tt = 0.f;
  int lastii = MAXIT - 1;
  int bi = 0;
  // scalar state (authoritative on block 0; uniform across its threads)
  float st_t = 1.f, st_r = 4.f;
  int oscF = 1, oscS = 0, kpos = 0, gap_ = 0;

  for (int ii = 0; ii < MAXIT; ++ii) {
    const int c0 = (ii == 0), pz = (ii <= 1);
    float*       xnw  = (ii & 1) ? wsX : out;   // x_old storage, overwritten by x_new
    const float* xcur = (ii & 1) ? out : wsX;   // x entering this iteration
    const float om = 1.f + tt;

    // zj[t] = (D @ y)[t, j]  from block-private u in LDS
    float zj[TDIM];
    #pragma unroll
    for (int t = 0; t < TDIM; ++t) {
      if (c0) zj[t] = 0.f;
      else {
        float a  = uL[(ii + 1) & 1][t][jl];     // D@x_ii
        float bb = pz ? 0.f : uL[ii & 1][t][jl]; // D@x_{ii-1}
        zj[t] = om * a - tt * bb;
      }
    }
    float zn[TDIM];
    #pragma unroll
    for (int t = 0; t < TDIM; ++t) zn[t] = 0.f;
    float vk = 0.f, cv = 0.f;

    for (int s = 0; s < KPT; ++s) {
      int k = k0 + s;
      int addr = ((b * KDIM + k) << 11) | p;
      float xcv = c0 ? 0.f : xcur[addr];
      float xov = pz ? 0.f : xnw[addr];
      float y   = c0 ? 0.f : om * xcv - tt * xov;
      float wd = 0.f, dt = 0.f;
      #pragma unroll
      for (int t = 0; t < TDIM; ++t) { wd += Dl[k][t] * zj[t]; dt += Dl[k][t] * Yreg[t]; }
      float v = y + linv * (dt - wd);           // y - linv*(DtD@y) + linv*DtY
      float xv = (v > lambd) ? v - lambd : ((v < -lambd) ? v + lambd : 0.f);
      xnw[addr] = xv;
      #pragma unroll
      for (int t = 0; t < TDIM; ++t) zn[t] += Dl[k][t] * xv;
      vk += (y - xv) * (xv - xcv);
      float d = xv - xcv; cv += d * d;
    }

    #pragma unroll
    for (int t = 0; t < TDIM; ++t) znL[kc][t][jl] = zn[t];
    red[tid] = vk; red2[tid] = cv;
    __syncthreads();
    // u_new (block-private): sum 16 k-chunk partials -> uL[ii&1]
    if (tid < TDIM * JPB) {
      int t = tid >> 4, j2 = tid & 15;
      float s = 0.f;
      #pragma unroll
      for (int c = 0; c < KCH; ++c) s += znL[c][t][j2];
      uL[ii & 1][t][j2] = s;
    }
    for (int o = NTHR >> 1; o > 0; o >>= 1) {
      if (tid < o) { red[tid] += red[tid + o]; red2[tid] += red2[tid + o]; }
      __syncthreads();
    }
    if (tid == 0) { ws[OFF_VKP + blk] = red[0]; ws[OFF_CVP + blk] = red2[0]; }

    ++bi; gbar(bar, NBLK * bi);

    // -------- scalar / control update on block 0 --------
    if (blk == 0) {
      red[tid]  = ws[OFF_VKP + tid];
      red2[tid] = ws[OFF_CVP + tid];
      __syncthreads();
      for (int o = NTHR >> 1; o > 0; o >>= 1) {
        if (tid < o) { red[tid] += red[tid + o]; red2[tid] += red2[tid + o]; }
        __syncthreads();
      }
      float vkt = red[0], cvt = red2[0];
      if (tid == 0) vkbufL[ii] = vkt;
      __syncthreads();

      int cond1 = oscF && (vkt >= 0.f);
      int Lg = ii - kpos;
      float sum_k = 0.f;
      if (Lg >= 3) {
        int i1 = ii - 1;   i1 = i1 < 0 ? 0 : (i1 > MAXIT - 1 ? MAXIT - 1 : i1);
        int i2 = kpos + 1; i2 = i2 < 0 ? 0 : (i2 > MAXIT - 1 ? MAXIT - 1 : i2);
        sum_k = sgnf(vkbufL[i1]) - sgnf(vkbufL[i2]);
      }
      int cond2 = oscS && (vkt <= 0.f) && (Lg >= 2 * gap_) && (sum_k == 0.f);

      float r_alpha = 0.f;
      if (cond1 || cond2) {
        float* xn = (ii & 1) ? wsX : out;       // x_new of this iteration
        for (int k = w; k < KDIM; k += 4) {
          float acc = 0.f;
          for (int idx = l; idx < NJ; idx += 64) {
            int b2 = idx >> 11, p2 = idx & (PDIM - 1);
            acc += xn[((b2 * KDIM + k) << 11) | p2];
          }
          #pragma unroll
          for (int o = 32; o > 0; o >>= 1) acc += __shfl_down(acc, o);
          if (l == 0) csum[k] = acc;
        }
        __syncthreads();
        float accE = 0.f;
        if (tid < 55) {
          int cnt = tid, ea = 0, eb = 0;
          for (int q = 0; q < TDIM; ++q) { int row = TDIM - q; if (cnt < row) { ea = q; eb = q + cnt; break; } cnt -= row; }
          for (int k = 0; k < KDIM; ++k) {
            float m = fabsf(csum[k] / (float)PDIM / (float)BDIM);
            if (m >= 1e-3f) accE += Dl[k][ea] * Dl[k][eb];
          }
        }
        if (w == 0) {
          for (int e2 = 0; e2 < 55; ++e2) {
            float vsh = __shfl(accE, e2);
            if (l == 0) {
              int cnt = e2, a2 = 0, b2 = 0;
              for (int q = 0; q < TDIM; ++q) { int row = TDIM - q; if (cnt < row) { a2 = q; b2 = q + cnt; break; } cnt -= row; }
              Mm[a2][b2] = (double)vsh; Mm[b2][a2] = (double)vsh;
            }
          }
        }
        __syncthreads();
        if (tid == 0) {
          for (int sw = 0; sw < 60; ++sw) {
            double off = 0.0;
            for (int a2 = 0; a2 < TDIM; ++a2)
              for (int b2 = a2 + 1; b2 < TDIM; ++b2) off += Mm[a2][b2] * Mm[a2][b2];
            if (off < 1e-22) break;
            for (int a2 = 0; a2 < TDIM - 1; ++a2)
              for (int b2 = a2 + 1; b2 < TDIM; ++b2) {
                double apq = Mm[a2][b2];
                if (fabs(apq) < 1e-30) continue;
                double app = Mm[a2][a2], aqq = Mm[b2][b2];
                double theta = (aqq - app) / (2.0 * apq);
                double tj = (theta >= 0.0 ? 1.0 : -1.0) / (fabs(theta) + sqrt(theta * theta + 1.0));
                double cj = 1.0 / sqrt(tj * tj + 1.0);
                double sj = tj * cj;
                for (int q2 = 0; q2 < TDIM; ++q2) {
                  double ap = Mm[a2][q2], aq = Mm[b2][q2];
                  Mm[a2][q2] = cj * ap - sj * aq;
                  Mm[b2][q2] = sj * ap + cj * aq;
                }
                for (int q2 = 0; q2 < TDIM; ++q2) {
                  double ap = Mm[q2][a2], aq = Mm[q2][b2];
                  Mm[q2][a2] = cj * ap - sj * aq;
                  Mm[q2][b2] = sj * ap + cj * aq;
                }
              }
          }
          float pmin = 3.4e38f; int found = 0;
          for (int a2 = 0; a2 < TDIM; ++a2) {
            float ev = (float)Mm[a2][a2];
            if (ev > 1e-4f) { if (ev < pmin) pmin = ev; found = 1; }
          }
          float pp = found ? pmin : 1.0f;
          float sq = sqrtf(linv * pp);
          bc[0] = 4.0f * (1.0f - sq) * (1.0f - sq) / (1.0f - pp * linv);
        }
        __syncthreads();
        r_alpha = bc[0];
      }

      float r1 = (r_alpha == 4.0f) ? 3.99f : r_alpha;
      float r_new = cond1 ? r1 : (cond2 ? r_alpha : st_r);
      float t_cur = cond1 ? (4.0f / (4.0f - r1) / 1.1f) : st_t;
      kpos = cond1 ? (ii + 10) : kpos;
      gap_ = cond1 ? ii : gap_;
      oscF = oscF && !cond1;
      oscS = cond1 ? 1 : (oscS && !cond2);
      float t_next = (1.f + sqrtf(1.f + r_new * t_cur * t_cur)) * 0.5f;
      float tt_new = (t_cur - 1.f) / t_next;
      float conv = sqrtf(cvt) / (c0 ? (float)PDIM : (float)KDIM);
      st_t = t_next; st_r = r_new;
      if (tid == 0) {
        __hip_atomic_store(&ws[OFF_SC + 0], tt_new, __ATOMIC_RELEASE, __HIP_MEMORY_SCOPE_AGENT);
        __hip_atomic_store(&ws[OFF_SC + 1], (conv < 0.01f) ? 1.f : 0.f,
                           __ATOMIC_RELEASE, __HIP_MEMORY_SCOPE_AGENT);
      }
    }

    ++bi; gbar(bar, NBLK * bi);

    tt = __hip_atomic_load(&ws[OFF_SC + 0], __ATOMIC_ACQUIRE, __HIP_MEMORY_SCOPE_AGENT);
    float dn = __hip_atomic_load(&ws[OFF_SC + 1], __ATOMIC_ACQUIRE, __HIP_MEMORY_SCOPE_AGENT);
    if (dn != 0.f) { lastii = ii; break; }
  }

  // final x = x_new@lastii: even lastii -> already in out; odd -> copy wsX -> out
  if (lastii & 1) {
    for (int idx = blk * NTHR + tid; idx < BDIM * KDIM * PDIM; idx += NBLK * NTHR)
      out[idx] = wsX[idx];
  }
}

extern "C" void kernel_launch(void* const* d_in, const int* in_sizes, int n_in,
                              void* d_out, int out_size, void* d_ws, size_t ws_size,
                              hipStream_t stream) {
  (void)in_sizes; (void)n_in; (void)out_size;
  if (ws_size < (size_t)WS_FLOATS * 4) return;
  const float* Y   = (const float*)d_in[0];
  const float* Drr = (const float*)d_in[1];
  const float* Dth = (const float*)d_in[2];
  float* out = (float*)d_out;
  float* ws  = (float*)d_ws;

  // zero the grid-barrier counter (graph-capture-legal; re-runs every replay)
  hipMemsetAsync(ws, 0, 64, stream);
  hipLaunchKernelGGL(k_persist, dim3(NBLK), dim3(NTHR), 0, stream, Y, Drr, Dth, ws, out);
}

// Round 5
// 76.757 us; speedup vs baseline: 2.8229x; 1.0215x over previous
//
#include <hip/hip_runtime.h>

#define NPOLE 160
#define KDIM  640
#define TDIM  10
#define PDIM  2048
#define BDIM  2
#define NJ    4096            // BDIM*PDIM
#define MAXIT 100
#define NBLK  256             // j-tiles of 16 columns each
#define NTHR  256
#define JPB   16              // j per block
#define KCH   16              // k-chunks per block
#define KPT   40              // k per thread

// ws layout (float offsets). First 16448 bytes are memset to 0 each launch.
#define OFF_ARR  0            // arrival flags: 256 x one-per-64B-line (4096 floats)
#define OFF_REL  4096         // packed 64-bit release {tt_bits, (ii+1)<<1|done}
#define OFF_VKP  4112         // 256 partial vk
#define OFF_CVP  4368         // 256 partial cv
#define OFF_XB   8192         // x ping-pong partner of d_out (2621440 floats)
#define WS_FLOATS (OFF_XB + BDIM*KDIM*PDIM)   // 2,629,632 floats = 10.52 MB
#define MEMSET_BYTES ((OFF_REL * 4) + 64)     // arrivals + release line

__device__ __forceinline__ float sgnf(float x) {
  return (x > 0.f) ? 1.f : ((x < 0.f) ? -1.f : 0.f);
}

__global__ void __launch_bounds__(NTHR)
k_persist(const float* __restrict__ Y, const float* __restrict__ Drr,
          const float* __restrict__ Dth, float* __restrict__ ws,
          float* __restrict__ out)
{
  const int tid = threadIdx.x, blk = blockIdx.x;
  const int w = tid >> 6, l = tid & 63;
  const int jl = tid & 15;            // j within tile
  const int kc = tid >> 4;            // k-chunk 0..15
  const int j = blk * JPB + jl;
  const int b = j >> 11, p = j & (PDIM - 1);
  const int k0 = kc * KPT;
  int* arr = (int*)ws;                               // arrival[i] at ((int*)ws)[i*16]
  unsigned long long* rel = (unsigned long long*)(ws + OFF_REL);

  __shared__ float Dl[KDIM][TDIM];        // 25.6 KB
  __shared__ float znL[KCH][TDIM][JPB];   // 10.2 KB
  __shared__ float uL[2][TDIM][JPB];      // block-private u = D@x
  __shared__ float red[NTHR], red2[NTHR];
  __shared__ float csum[KDIM];
  __shared__ float Msh[64];
  __shared__ double Mm[TDIM][TDIM];
  __shared__ float vkbufL[MAXIT];
  __shared__ float bc[2];

  // ---- build normalized dictionary into LDS (redundant per block) ----
  for (int k = tid; k < KDIM; k += NTHR) {
    int n = k % NPOLE, grp = k / NPOLE;
    float r = Drr[n], th = Dth[n];
    float col[TDIM]; float ss = 0.f, ri = 1.f;
    #pragma unroll
    for (int i = 0; i < TDIM; ++i) {
      float ang = (float)i * th;
      float c = cosf(ang), s = sinf(ang);
      float sgn = (i & 1) ? -1.f : 1.f;
      float v = (grp == 0) ? ri * c : (grp == 1) ? sgn * ri * c
               : (grp == 2) ? ri * s : sgn * ri * s;
      col[i] = v; ss += v * v; ri *= r;
    }
    float G = sqrtf(ss); if (G == 0.f) G = sqrtf((float)TDIM);
    float gi = 1.f / G;
    #pragma unroll
    for (int i = 0; i < TDIM; ++i) Dl[k][i] = col[i] * gi;
  }
  __syncthreads();

  // ---- L = ||DtD||_F via 10x10 D·D^T Frobenius identity (redundant) ----
  for (int e = w; e < 55; e += 4) {
    int cnt = e, t1 = 0, t2 = 0;
    for (int q = 0; q < TDIM; ++q) { int row = TDIM - q; if (cnt < row) { t1 = q; t2 = q + cnt; break; } cnt -= row; }
    float acc = 0.f;
    for (int k = l; k < KDIM; k += 64) acc += Dl[k][t1] * Dl[k][t2];
    #pragma unroll
    for (int o = 32; o > 0; o >>= 1) acc += __shfl_down(acc, o);
    if (l == 0) Msh[e] = acc;
  }
  __syncthreads();
  float fro = 0.f;
  {
    int e = 0;
    for (int t1 = 0; t1 < TDIM; ++t1)
      for (int t2 = t1; t2 < TDIM; ++t2, ++e) {
        float m = Msh[e];
        fro += (t1 == t2 ? 1.f : 2.f) * m * m;
      }
  }
  const float linv = 1.f / sqrtf(fro);
  const float lambd = 0.1f * linv;

  float Yreg[TDIM];
  #pragma unroll
  for (int t = 0; t < TDIM; ++t) Yreg[t] = Y[(b * TDIM + t) * PDIM + p];

  float* wsX = ws + OFF_XB;

  float tt = 0.f;
  int lastii = MAXIT - 1;
  // scalar state (authoritative on block 0; uniform across its threads)
  float st_t = 1.f, st_r = 4.f;
  int oscF = 1, oscS = 0, kpos = 0, gap_ = 0;

  for (int ii = 0; ii < MAXIT; ++ii) {
    const int c0 = (ii == 0), pz = (ii <= 1);
    float*       xnw  = (ii & 1) ? wsX : out;   // x_old storage, overwritten by x_new
    const float* xcur = (ii & 1) ? out : wsX;   // x entering this iteration
    const float om = 1.f + tt;

    // zj[t] = (D @ y)[t, j]  from block-private u in LDS
    float zj[TDIM];
    #pragma unroll
    for (int t = 0; t < TDIM; ++t) {
      if (c0) zj[t] = 0.f;
      else {
        float a  = uL[(ii + 1) & 1][t][jl];      // D@x_ii
        float bb = pz ? 0.f : uL[ii & 1][t][jl]; // D@x_{ii-1}
        zj[t] = om * a - tt * bb;
      }
    }
    float zn[TDIM];
    #pragma unroll
    for (int t = 0; t < TDIM; ++t) zn[t] = 0.f;
    float vk = 0.f, cv = 0.f;

    for (int s = 0; s < KPT; ++s) {
      int k = k0 + s;
      int addr = ((b * KDIM + k) << 11) | p;
      float xcv = c0 ? 0.f : xcur[addr];
      float xov = pz ? 0.f : xnw[addr];
      float y   = c0 ? 0.f : om * xcv - tt * xov;
      float wd = 0.f, dt = 0.f;
      #pragma unroll
      for (int t = 0; t < TDIM; ++t) { wd += Dl[k][t] * zj[t]; dt += Dl[k][t] * Yreg[t]; }
      float v = y + linv * (dt - wd);           // y - linv*(DtD@y) + linv*DtY
      float xv = (v > lambd) ? v - lambd : ((v < -lambd) ? v + lambd : 0.f);
      xnw[addr] = xv;
      #pragma unroll
      for (int t = 0; t < TDIM; ++t) zn[t] += Dl[k][t] * xv;
      vk += (y - xv) * (xv - xcv);
      float d = xv - xcv; cv += d * d;
    }

    #pragma unroll
    for (int t = 0; t < TDIM; ++t) znL[kc][t][jl] = zn[t];
    red[tid] = vk; red2[tid] = cv;
    __syncthreads();
    // u_new (block-private): sum 16 k-chunk partials -> uL[ii&1]
    if (tid < TDIM * JPB) {
      int t = tid >> 4, j2 = tid & 15;
      float s = 0.f;
      #pragma unroll
      for (int c = 0; c < KCH; ++c) s += znL[c][t][j2];
      uL[ii & 1][t][j2] = s;
    }
    for (int o = NTHR >> 1; o > 0; o >>= 1) {
      if (tid < o) { red[tid] += red[tid + o]; red2[tid] += red2[tid + o]; }
      __syncthreads();
    }
    // ---- arrival: partials + per-block flag on its own cache line ----
    if (tid == 0) {
      ws[OFF_VKP + blk] = red[0];
      ws[OFF_CVP + blk] = red2[0];
      __hip_atomic_store(&arr[blk * 16], ii + 1, __ATOMIC_RELEASE, __HIP_MEMORY_SCOPE_AGENT);
    }

    if (blk == 0) {
      // each thread polls one arrival flag (distinct lines, parallel)
      int guard = 0;
      while (__hip_atomic_load(&arr[tid * 16], __ATOMIC_ACQUIRE, __HIP_MEMORY_SCOPE_AGENT) < ii + 1) {
        __builtin_amdgcn_s_sleep(2);
        if (++guard > (1 << 22)) break;
      }
      float pvk = ws[OFF_VKP + tid];   // paired with this thread's acquire
      float pcv = ws[OFF_CVP + tid];
      __syncthreads();
      __threadfence();                 // make remote x_new visible to all lanes (eigen path)
      red[tid] = pvk; red2[tid] = pcv;
      __syncthreads();
      for (int o = NTHR >> 1; o > 0; o >>= 1) {
        if (tid < o) { red[tid] += red[tid + o]; red2[tid] += red2[tid + o]; }
        __syncthreads();
      }
      float vkt = red[0], cvt = red2[0];
      if (tid == 0) vkbufL[ii] = vkt;
      __syncthreads();

      int cond1 = oscF && (vkt >= 0.f);
      int Lg = ii - kpos;
      float sum_k = 0.f;
      if (Lg >= 3) {
        int i1 = ii - 1;   i1 = i1 < 0 ? 0 : (i1 > MAXIT - 1 ? MAXIT - 1 : i1);
        int i2 = kpos + 1; i2 = i2 < 0 ? 0 : (i2 > MAXIT - 1 ? MAXIT - 1 : i2);
        sum_k = sgnf(vkbufL[i1]) - sgnf(vkbufL[i2]);
      }
      int cond2 = oscS && (vkt <= 0.f) && (Lg >= 2 * gap_) && (sum_k == 0.f);

      float r_alpha = 0.f;
      if (cond1 || cond2) {
        float* xn = (ii & 1) ? wsX : out;       // x_new of this iteration
        for (int k = w; k < KDIM; k += 4) {
          float acc = 0.f;
          for (int idx = l; idx < NJ; idx += 64) {
            int b2 = idx >> 11, p2 = idx & (PDIM - 1);
            acc += xn[((b2 * KDIM + k) << 11) | p2];
          }
          #pragma unroll
          for (int o = 32; o > 0; o >>= 1) acc += __shfl_down(acc, o);
          if (l == 0) csum[k] = acc;
        }
        __syncthreads();
        float accE = 0.f;
        if (tid < 55) {
          int cnt = tid, ea = 0, eb = 0;
          for (int q = 0; q < TDIM; ++q) { int row = TDIM - q; if (cnt < row) { ea = q; eb = q + cnt; break; } cnt -= row; }
          for (int k = 0; k < KDIM; ++k) {
            float m = fabsf(csum[k] / (float)PDIM / (float)BDIM);
            if (m >= 1e-3f) accE += Dl[k][ea] * Dl[k][eb];
          }
        }
        if (w == 0) {
          for (int e2 = 0; e2 < 55; ++e2) {
            float vsh = __shfl(accE, e2);
            if (l == 0) {
              int cnt = e2, a2 = 0, b2 = 0;
              for (int q = 0; q < TDIM; ++q) { int row = TDIM - q; if (cnt < row) { a2 = q; b2 = q + cnt; break; } cnt -= row; }
              Mm[a2][b2] = (double)vsh; Mm[b2][a2] = (double)vsh;
            }
          }
        }
        __syncthreads();
        if (tid == 0) {
          for (int sw = 0; sw < 60; ++sw) {
            double off = 0.0;
            for (int a2 = 0; a2 < TDIM; ++a2)
              for (int b2 = a2 + 1; b2 < TDIM; ++b2) off += Mm[a2][b2] * Mm[a2][b2];
            if (off < 1e-22) break;
            for (int a2 = 0; a2 < TDIM - 1; ++a2)
              for (int b2 = a2 + 1; b2 < TDIM; ++b2) {
                double apq = Mm[a2][b2];
                if (fabs(apq) < 1e-30) continue;
                double app = Mm[a2][a2], aqq = Mm[b2][b2];
                double theta = (aqq - app) / (2.0 * apq);
                double tj = (theta >= 0.0 ? 1.0 : -1.0) / (fabs(theta) + sqrt(theta * theta + 1.0));
                double cj = 1.0 / sqrt(tj * tj + 1.0);
                double sj = tj * cj;
                for (int q2 = 0; q2 < TDIM; ++q2) {
                  double ap = Mm[a2][q2], aq = Mm[b2][q2];
                  Mm[a2][q2] = cj * ap - sj * aq;
                  Mm[b2][q2] = sj * ap + cj * aq;
                }
                for (int q2 = 0; q2 < TDIM; ++q2) {
                  double ap = Mm[q2][a2], aq = Mm[q2][b2];
                  Mm[q2][a2] = cj * ap - sj * aq;
                  Mm[q2][b2] = sj * ap + cj * aq;
                }
              }
          }
          float pmin = 3.4e38f; int found = 0;
          for (int a2 = 0; a2 < TDIM; ++a2) {
            float ev = (float)Mm[a2][a2];
            if (ev > 1e-4f) { if (ev < pmin) pmin = ev; found = 1; }
          }
          float pp = found ? pmin : 1.0f;
          float sq = sqrtf(linv * pp);
          bc[0] = 4.0f * (1.0f - sq) * (1.0f - sq) / (1.0f - pp * linv);
        }
        __syncthreads();
        r_alpha = bc[0];
      }

      float r1 = (r_alpha == 4.0f) ? 3.99f : r_alpha;
      float r_new = cond1 ? r1 : (cond2 ? r_alpha : st_r);
      float t_cur = cond1 ? (4.0f / (4.0f - r1) / 1.1f) : st_t;
      kpos = cond1 ? (ii + 10) : kpos;
      gap_ = cond1 ? ii : gap_;
      oscF = oscF && !cond1;
      oscS = cond1 ? 1 : (oscS && !cond2);
      float t_next = (1.f + sqrtf(1.f + r_new * t_cur * t_cur)) * 0.5f;
      float tt_new = (t_cur - 1.f) / t_next;
      float conv = sqrtf(cvt) / (c0 ? (float)PDIM : (float)KDIM);
      st_t = t_next; st_r = r_new;
      int done = (conv < 0.01f) ? 1 : 0;
      if (tid == 0) {
        unsigned long long pack =
            ((unsigned long long)__float_as_uint(tt_new) << 32)
          | ((unsigned long long)(unsigned)((ii + 1) << 1)) | (unsigned long long)done;
        __hip_atomic_store(rel, pack, __ATOMIC_RELEASE, __HIP_MEMORY_SCOPE_AGENT);
      }
      tt = tt_new;
      if (done) { lastii = ii; break; }
    } else {
      // one lane polls the single release line; others wait at __syncthreads
      if (tid == 0) {
        int guard = 0;
        unsigned long long pack;
        for (;;) {
          pack = __hip_atomic_load(rel, __ATOMIC_ACQUIRE, __HIP_MEMORY_SCOPE_AGENT);
          if ((int)(((unsigned)pack) >> 1) >= ii + 1) break;
          __builtin_amdgcn_s_sleep(2);
          if (++guard > (1 << 22)) break;
        }
        bc[0] = __uint_as_float((unsigned)(pack >> 32));
        bc[1] = (float)((unsigned)pack & 1u);
      }
      __syncthreads();
      tt = bc[0];
      float dn = bc[1];
      __syncthreads();
      if (dn != 0.f) { lastii = ii; break; }
    }
  }

  // final x = x_new@lastii: even lastii -> already in out; odd -> copy wsX -> out
  if (lastii & 1) {
    __threadfence();
    for (int idx = blk * NTHR + tid; idx < BDIM * KDIM * PDIM; idx += NBLK * NTHR)
      out[idx] = wsX[idx];
  }
}

extern "C" void kernel_launch(void* const* d_in, const int* in_sizes, int n_in,
                              void* d_out, int out_size, void* d_ws, size_t ws_size,
                              hipStream_t stream) {
  (void)in_sizes; (void)n_in; (void)out_size;
  if (ws_size < (size_t)WS_FLOATS * 4) return;
  const float* Y   = (const float*)d_in[0];
  const float* Drr = (const float*)d_in[1];
  const float* Dth = (const float*)d_in[2];
  float* out = (float*)d_out;
  float* ws  = (float*)d_ws;

  // reset arrival flags + release word (graph-capture-legal; re-runs every replay)
  hipMemsetAsync(ws, 0, MEMSET_BYTES, stream);
  hipLaunchKernelGGL(k_persist, dim3(NBLK), dim3(NTHR), 0, stream, Y, Drr, Dth, ws, out);
}

// Round 6
// 53.419 us; speedup vs baseline: 4.0562x; 1.4369x over previous
//
#include <hip/hip_runtime.h>

#define NPOLE 160
#define KDIM  640
#define TDIM  10
#define PDIM  2048
#define BDIM  2
#define NJ    4096            // BDIM*PDIM
#define MAXIT 100
#define NBLK  128             // j-tiles of 32 columns (one full 128B line)
#define NTHR  256
#define JPB   32              // j per block
#define KCH   8               // k-chunks per block
#define KPT   80              // k per thread

// ws layout (float offsets). First 4096 BYTES memset to 0 each launch.
#define OFF_SLOT 0            // u64 slot[2][NBLK]: payload {cv+1 | vk}, hi!=0 == arrived
#define OFF_REL  768          // u64: {tt_bits<<32 | seq<<3 | flush<<2 | done}
#define OFF_XB   2048         // x ping-pong partner of d_out (2621440 floats)
#define WS_FLOATS (OFF_XB + BDIM*KDIM*PDIM)   // 10.49 MB
#define MEMSET_BYTES 4096

#define SEQ(wv)   ((int)(((wv) >> 3) & 0x1FFFFFFF))
#define FLUSH(wv) ((int)(((wv) >> 2) & 1))
#define DONE(wv)  ((int)((wv) & 1))

__device__ __forceinline__ float sgnf(float x) {
  return (x > 0.f) ? 1.f : ((x < 0.f) ? -1.f : 0.f);
}

__global__ void __launch_bounds__(NTHR)
k_persist(const float* __restrict__ Y, const float* __restrict__ Drr,
          const float* __restrict__ Dth, float* __restrict__ ws,
          float* __restrict__ out)
{
  const int tid = threadIdx.x, blk = blockIdx.x;
  const int w = tid >> 6, l = tid & 63;
  const int jl = tid & 31;            // j within tile
  const int kc = tid >> 5;            // k-chunk 0..7
  const int j = blk * JPB + jl;
  const int b = j >> 11, p = j & (PDIM - 1);
  const int k0 = kc * KPT;
  unsigned long long* slot = (unsigned long long*)(ws + OFF_SLOT);
  unsigned long long* rel  = (unsigned long long*)(ws + OFF_REL);

  __shared__ float Dl[KDIM][TDIM];        // 25.6 KB
  __shared__ float znL[KCH][TDIM][JPB];   // 10.2 KB
  __shared__ float uL[2][TDIM][JPB];      // block-private u = D@x
  __shared__ float red[NTHR], red2[NTHR];
  __shared__ float csum[KDIM];
  __shared__ float Msh[64];
  __shared__ double Mm[TDIM][TDIM];
  __shared__ float vkbufL[MAXIT];
  __shared__ float bcf[4];

  // ---- build normalized dictionary into LDS (redundant per block) ----
  for (int k = tid; k < KDIM; k += NTHR) {
    int n = k % NPOLE, grp = k / NPOLE;
    float r = Drr[n], th = Dth[n];
    float col[TDIM]; float ss = 0.f, ri = 1.f;
    #pragma unroll
    for (int i = 0; i < TDIM; ++i) {
      float ang = (float)i * th;
      float c = cosf(ang), s = sinf(ang);
      float sgn = (i & 1) ? -1.f : 1.f;
      float v = (grp == 0) ? ri * c : (grp == 1) ? sgn * ri * c
               : (grp == 2) ? ri * s : sgn * ri * s;
      col[i] = v; ss += v * v; ri *= r;
    }
    float G = sqrtf(ss); if (G == 0.f) G = sqrtf((float)TDIM);
    float gi = 1.f / G;
    #pragma unroll
    for (int i = 0; i < TDIM; ++i) Dl[k][i] = col[i] * gi;
  }
  __syncthreads();

  // ---- L = ||DtD||_F via 10x10 D·D^T Frobenius identity (redundant) ----
  for (int e = w; e < 55; e += 4) {
    int cnt = e, t1 = 0, t2 = 0;
    for (int q = 0; q < TDIM; ++q) { int row = TDIM - q; if (cnt < row) { t1 = q; t2 = q + cnt; break; } cnt -= row; }
    float acc = 0.f;
    for (int k = l; k < KDIM; k += 64) acc += Dl[k][t1] * Dl[k][t2];
    #pragma unroll
    for (int o = 32; o > 0; o >>= 1) acc += __shfl_down(acc, o);
    if (l == 0) Msh[e] = acc;
  }
  __syncthreads();
  float fro = 0.f;
  {
    int e = 0;
    for (int t1 = 0; t1 < TDIM; ++t1)
      for (int t2 = t1; t2 < TDIM; ++t2, ++e) {
        float m = Msh[e];
        fro += (t1 == t2 ? 1.f : 2.f) * m * m;
      }
  }
  const float linv = 1.f / sqrtf(fro);
  const float lambd = 0.1f * linv;

  float Yreg[TDIM];
  #pragma unroll
  for (int t = 0; t < TDIM; ++t) Yreg[t] = Y[(b * TDIM + t) * PDIM + p];

  float* wsX = ws + OFF_XB;

  float tt = 0.f;
  int lastii = MAXIT - 1;
  int relcnt = 0;   // block0: releases made; workers (tid0): releases consumed
  // scalar state (authoritative on block 0; uniform across its threads)
  float st_t = 1.f, st_r = 4.f;
  int oscF = 1, oscS = 0, kpos = 0, gap_ = 0;

  for (int ii = 0; ii < MAXIT; ++ii) {
    const int c0 = (ii == 0), pz = (ii <= 1);
    const int pr = ii & 1;
    float*       xnw  = pr ? wsX : out;   // x_old storage, overwritten by x_new
    const float* xcur = pr ? out : wsX;   // x entering this iteration
    const float om = 1.f + tt;

    // zj[t] = (D @ y)[t, j]  from block-private u in LDS
    float zj[TDIM];
    #pragma unroll
    for (int t = 0; t < TDIM; ++t) {
      if (c0) zj[t] = 0.f;
      else {
        float a  = uL[pr ^ 1][t][jl];          // D@x_ii
        float bb = pz ? 0.f : uL[pr][t][jl];   // D@x_{ii-1}
        zj[t] = om * a - tt * bb;
      }
    }
    float zn[TDIM];
    #pragma unroll
    for (int t = 0; t < TDIM; ++t) zn[t] = 0.f;
    float vk = 0.f, cv = 0.f;

    for (int s = 0; s < KPT; ++s) {
      int k = k0 + s;
      int addr = ((b * KDIM + k) << 11) | p;
      float xcv = c0 ? 0.f : xcur[addr];
      float xov = pz ? 0.f : xnw[addr];
      float y   = c0 ? 0.f : om * xcv - tt * xov;
      float wd = 0.f, dt = 0.f;
      #pragma unroll
      for (int t = 0; t < TDIM; ++t) { wd += Dl[k][t] * zj[t]; dt += Dl[k][t] * Yreg[t]; }
      float v = y + linv * (dt - wd);           // y - linv*(DtD@y) + linv*DtY
      float xv = (v > lambd) ? v - lambd : ((v < -lambd) ? v + lambd : 0.f);
      xnw[addr] = xv;
      #pragma unroll
      for (int t = 0; t < TDIM; ++t) zn[t] += Dl[k][t] * xv;
      vk += (y - xv) * (xv - xcv);
      float d = xv - xcv; cv += d * d;
    }

    #pragma unroll
    for (int t = 0; t < TDIM; ++t) znL[kc][t][jl] = zn[t];
    red[tid] = vk; red2[tid] = cv;
    __syncthreads();
    // u_new (block-private): sum KCH k-chunk partials -> uL[pr]
    for (int i = tid; i < TDIM * JPB; i += NTHR) {
      int t = i >> 5, j2 = i & 31;
      float s = 0.f;
      #pragma unroll
      for (int c = 0; c < KCH; ++c) s += znL[c][t][j2];
      uL[pr][t][j2] = s;
    }
    for (int o = NTHR >> 1; o > 0; o >>= 1) {
      if (tid < o) { red[tid] += red[tid + o]; red2[tid] += red2[tid + o]; }
      __syncthreads();
    }
    // ---- arrival: {vk, cv} packed INSIDE the flag word (no fence needed) ----
    if (tid == 0) {
      unsigned long long pay =
          ((unsigned long long)__float_as_uint(red2[0] + 1.0f) << 32)
        | (unsigned long long)__float_as_uint(red[0]);
      __hip_atomic_store(&slot[pr * NBLK + blk], pay, __ATOMIC_RELAXED, __HIP_MEMORY_SCOPE_AGENT);
    }

    if (blk == 0) {
      // consume arrivals: each of 128 threads polls one slot (relaxed, no inv)
      float pvk = 0.f, pcv = 0.f;
      if (tid < NBLK) {
        unsigned long long v; int g = 0;
        for (;;) {
          v = __hip_atomic_load(&slot[pr * NBLK + tid], __ATOMIC_RELAXED, __HIP_MEMORY_SCOPE_AGENT);
          if ((unsigned)(v >> 32) != 0u) break;
          __builtin_amdgcn_s_sleep(4);
          if (++g > (1 << 22)) break;
        }
        pvk = __uint_as_float((unsigned)v);
        pcv = __uint_as_float((unsigned)(v >> 32)) - 1.0f;
        // zero for reuse at ii+2 (ordered before release by its vmcnt wait)
        __hip_atomic_store(&slot[pr * NBLK + tid], 0ULL, __ATOMIC_RELAXED, __HIP_MEMORY_SCOPE_AGENT);
      }
      red[tid] = pvk; red2[tid] = pcv;
      __syncthreads();
      for (int o = NTHR >> 1; o > 0; o >>= 1) {
        if (tid < o) { red[tid] += red[tid + o]; red2[tid] += red2[tid + o]; }
        __syncthreads();
      }
      float vkt = red[0], cvt = red2[0];
      if (tid == 0) vkbufL[ii] = vkt;
      __syncthreads();

      int cond1 = oscF && (vkt >= 0.f);
      int Lg = ii - kpos;
      float sum_k = 0.f;
      if (Lg >= 3) {
        int i1 = ii - 1;   i1 = i1 < 0 ? 0 : (i1 > MAXIT - 1 ? MAXIT - 1 : i1);
        int i2 = kpos + 1; i2 = i2 < 0 ? 0 : (i2 > MAXIT - 1 ? MAXIT - 1 : i2);
        sum_k = sgnf(vkbufL[i1]) - sgnf(vkbufL[i2]);
      }
      int cond2 = oscS && (vkt <= 0.f) && (Lg >= 2 * gap_) && (sum_k == 0.f);

      float r_alpha = 0.f;
      if (cond1 || cond2) {
        // RARE path: need cross-block x. Flush protocol:
        ++relcnt;
        if (tid == 0) {
          unsigned long long wv = ((unsigned long long)(unsigned)relcnt << 3) | 4ULL;
          __hip_atomic_store(rel, wv, __ATOMIC_RELEASE, __HIP_MEMORY_SCOPE_AGENT);
          // own ack (self x is locally coherent)
          __hip_atomic_store(&slot[(pr ^ 1) * NBLK + 0], 1ULL << 32, __ATOMIC_RELAXED, __HIP_MEMORY_SCOPE_AGENT);
        }
        if (tid < NBLK) {             // wait all flush-acks
          int g = 0;
          while ((unsigned)(__hip_atomic_load(&slot[(pr ^ 1) * NBLK + tid], __ATOMIC_RELAXED,
                                              __HIP_MEMORY_SCOPE_AGENT) >> 32) == 0u) {
            __builtin_amdgcn_s_sleep(4);
            if (++g > (1 << 22)) break;
          }
        }
        __syncthreads();
        if (tid == 0) __threadfence();   // acquire side: invalidate stale clean lines
        __syncthreads();
        if (tid < NBLK)                  // re-zero ack slots for iteration pr^1
          __hip_atomic_store(&slot[(pr ^ 1) * NBLK + tid], 0ULL, __ATOMIC_RELAXED, __HIP_MEMORY_SCOPE_AGENT);

        float* xn = pr ? wsX : out;      // x_new of this iteration (now visible)
        for (int k = w; k < KDIM; k += 4) {
          float acc = 0.f;
          for (int idx = l; idx < NJ; idx += 64) {
            int b2 = idx >> 11, p2 = idx & (PDIM - 1);
            acc += xn[((b2 * KDIM + k) << 11) | p2];
          }
          #pragma unroll
          for (int o = 32; o > 0; o >>= 1) acc += __shfl_down(acc, o);
          if (l == 0) csum[k] = acc;
        }
        __syncthreads();
        float accE = 0.f;
        if (tid < 55) {
          int cnt = tid, ea = 0, eb = 0;
          for (int q = 0; q < TDIM; ++q) { int row = TDIM - q; if (cnt < row) { ea = q; eb = q + cnt; break; } cnt -= row; }
          for (int k = 0; k < KDIM; ++k) {
            float m = fabsf(csum[k] / (float)PDIM / (float)BDIM);
            if (m >= 1e-3f) accE += Dl[k][ea] * Dl[k][eb];
          }
        }
        if (w == 0) {
          for (int e2 = 0; e2 < 55; ++e2) {
            float vsh = __shfl(accE, e2);
            if (l == 0) {
              int cnt = e2, a2 = 0, b2 = 0;
              for (int q = 0; q < TDIM; ++q) { int row = TDIM - q; if (cnt < row) { a2 = q; b2 = q + cnt; break; } cnt -= row; }
              Mm[a2][b2] = (double)vsh; Mm[b2][a2] = (double)vsh;
            }
          }
        }
        __syncthreads();
        if (tid == 0) {
          for (int sw = 0; sw < 60; ++sw) {
            double off = 0.0;
            for (int a2 = 0; a2 < TDIM; ++a2)
              for (int b2 = a2 + 1; b2 < TDIM; ++b2) off += Mm[a2][b2] * Mm[a2][b2];
            if (off < 1e-22) break;
            for (int a2 = 0; a2 < TDIM - 1; ++a2)
              for (int b2 = a2 + 1; b2 < TDIM; ++b2) {
                double apq = Mm[a2][b2];
                if (fabs(apq) < 1e-30) continue;
                double app = Mm[a2][a2], aqq = Mm[b2][b2];
                double theta = (aqq - app) / (2.0 * apq);
                double tj = (theta >= 0.0 ? 1.0 : -1.0) / (fabs(theta) + sqrt(theta * theta + 1.0));
                double cj = 1.0 / sqrt(tj * tj + 1.0);
                double sj = tj * cj;
                for (int q2 = 0; q2 < TDIM; ++q2) {
                  double ap = Mm[a2][q2], aq = Mm[b2][q2];
                  Mm[a2][q2] = cj * ap - sj * aq;
                  Mm[b2][q2] = sj * ap + cj * aq;
                }
                for (int q2 = 0; q2 < TDIM; ++q2) {
                  double ap = Mm[q2][a2], aq = Mm[q2][b2];
                  Mm[q2][a2] = cj * ap - sj * aq;
                  Mm[q2][b2] = sj * ap + cj * aq;
                }
              }
          }
          float pmin = 3.4e38f; int found = 0;
          for (int a2 = 0; a2 < TDIM; ++a2) {
            float ev = (float)Mm[a2][a2];
            if (ev > 1e-4f) { if (ev < pmin) pmin = ev; found = 1; }
          }
          float pp = found ? pmin : 1.0f;
          float sq = sqrtf(linv * pp);
          bcf[0] = 4.0f * (1.0f - sq) * (1.0f - sq) / (1.0f - pp * linv);
        }
        __syncthreads();
        r_alpha = bcf[0];
      }

      float r1 = (r_alpha == 4.0f) ? 3.99f : r_alpha;
      float r_new = cond1 ? r1 : (cond2 ? r_alpha : st_r);
      float t_cur = cond1 ? (4.0f / (4.0f - r1) / 1.1f) : st_t;
      kpos = cond1 ? (ii + 10) : kpos;
      gap_ = cond1 ? ii : gap_;
      oscF = oscF && !cond1;
      oscS = cond1 ? 1 : (oscS && !cond2);
      float t_next = (1.f + sqrtf(1.f + r_new * t_cur * t_cur)) * 0.5f;
      float tt_new = (t_cur - 1.f) / t_next;
      float conv = sqrtf(cvt) / (c0 ? (float)PDIM : (float)KDIM);
      st_t = t_next; st_r = r_new;
      int done = (conv < 0.01f) ? 1 : 0;
      ++relcnt;
      if (tid == 0) {
        unsigned long long wv =
            ((unsigned long long)__float_as_uint(tt_new) << 32)
          | ((unsigned long long)(unsigned)relcnt << 3) | (unsigned long long)done;
        __hip_atomic_store(rel, wv, __ATOMIC_RELEASE, __HIP_MEMORY_SCOPE_AGENT);
      }
      tt = tt_new;
      if (done) { lastii = ii; break; }
    } else {
      // ---- worker: poll release word (relaxed; payload rides in the word) ----
      if (tid == 0) {
        int exps = relcnt + 1;
        for (;;) {
          unsigned long long wv; int g = 0;
          for (;;) {
            wv = __hip_atomic_load(rel, __ATOMIC_RELAXED, __HIP_MEMORY_SCOPE_AGENT);
            if (SEQ(wv) >= exps) break;
            __builtin_amdgcn_s_sleep(4);
            if (++g > (1 << 22)) break;
          }
          if (FLUSH(wv) && SEQ(wv) == exps) {
            __threadfence();             // push this block's dirty x to coherence point
            __hip_atomic_store(&slot[(pr ^ 1) * NBLK + blk], 1ULL << 32,
                               __ATOMIC_RELAXED, __HIP_MEMORY_SCOPE_AGENT);
            ++exps;
            continue;
          }
          relcnt = exps;
          bcf[0] = __uint_as_float((unsigned)(wv >> 32));
          bcf[1] = (float)DONE(wv);
          break;
        }
      }
      __syncthreads();
      tt = bcf[0];
      float dn = bcf[1];
      __syncthreads();
      if (dn != 0.f) { lastii = ii; break; }
    }
  }

  // final x = x_new@lastii: even -> already in out; odd -> copy OWN region wsX->out
  if (lastii & 1) {
    for (int s = 0; s < KPT; ++s) {
      int k = k0 + s;
      int addr = ((b * KDIM + k) << 11) | p;
      out[addr] = wsX[addr];
    }
  }
}

extern "C" void kernel_launch(void* const* d_in, const int* in_sizes, int n_in,
                              void* d_out, int out_size, void* d_ws, size_t ws_size,
                              hipStream_t stream) {
  (void)in_sizes; (void)n_in; (void)out_size;
  if (ws_size < (size_t)WS_FLOATS * 4) return;
  const float* Y   = (const float*)d_in[0];
  const float* Drr = (const float*)d_in[1];
  const float* Dth = (const float*)d_in[2];
  float* out = (float*)d_out;
  float* ws  = (float*)d_ws;

  // reset slots + release word (graph-capture-legal; re-runs every replay)
  hipMemsetAsync(ws, 0, MEMSET_BYTES, stream);
  hipLaunchKernelGGL(k_persist, dim3(NBLK), dim3(NTHR), 0, stream, Y, Drr, Dth, ws, out);
}

// Round 7
// 41.481 us; speedup vs baseline: 5.2235x; 1.2878x over previous
//
#include <hip/hip_runtime.h>

#define NPOLE 160
#define KDIM  640
#define TDIM  10
#define PDIM  2048
#define BDIM  2
#define NJ    4096            // BDIM*PDIM
#define MAXIT 100

// ---- k_iter0 geometry: 256 blocks x 512 threads, 2-way k-split ----
#define NBI   256
#define NTI   512
#define KGI   16              // k-groups per block
#define KPTI  20              // k per thread
// ---- k_rest geometry (round-6 proven) ----
#define NBLK  128
#define NTHR  256
#define JPB   32
#define KCH   8
#define KPT   80

// ws float offsets. First MEMSET_BYTES zeroed each launch.
#define OFF_SLOT 0            // u64 slot[2][NBLK] (2048 floats)
#define OFF_REL  2048         // u64 release word
#define OFF_SC   2064         // [0]=linv [1]=lambd
#define OFF_VKP  2176         // 256 vk partials (k_iter0)
#define OFF_CVP  2432         // 256 cv partials
#define OFF_D    2688         // 6400, layout [t][k]
#define OFF_U2   9088         // 2 x 40960 per-ks u partials
#define OFF_XB   91008        // 2621440 x ping-pong partner of d_out
#define WS_FLOATS (OFF_XB + BDIM*KDIM*PDIM)   // 10.85 MB
#define MEMSET_BYTES (OFF_SC * 4)

#define SEQ(wv)   ((int)(((wv) >> 3) & 0x1FFFFFFF))
#define FLUSH(wv) ((int)(((wv) >> 2) & 1))
#define DONE(wv)  ((int)((wv) & 1))

__device__ __forceinline__ float sgnf(float x) {
  return (x > 0.f) ? 1.f : ((x < 0.f) ? -1.f : 0.f);
}
__device__ __forceinline__ float shrinkf(float v, float lam) {
  return (v > lam) ? v - lam : ((v < -lam) ? v + lam : 0.f);
}

// masked-dictionary alpha (shared by entry + loop paths; block-uniform call)
__device__ float alpha_eval(const float* __restrict__ xn, const float (*Dl)[TDIM],
                            float* csum, double (*Mm)[TDIM], float* bcf,
                            float linv, int w, int l, int tid) {
  for (int k = w; k < KDIM; k += 4) {
    float acc = 0.f;
    for (int idx = l; idx < NJ; idx += 64) {
      int b2 = idx >> 11, p2 = idx & (PDIM - 1);
      acc += xn[((b2 * KDIM + k) << 11) | p2];
    }
    #pragma unroll
    for (int o = 32; o > 0; o >>= 1) acc += __shfl_down(acc, o);
    if (l == 0) csum[k] = acc;
  }
  __syncthreads();
  float accE = 0.f;
  if (tid < 55) {
    int cnt = tid, ea = 0, eb = 0;
    for (int q = 0; q < TDIM; ++q) { int row = TDIM - q; if (cnt < row) { ea = q; eb = q + cnt; break; } cnt -= row; }
    for (int k = 0; k < KDIM; ++k) {
      float m = fabsf(csum[k] / (float)PDIM / (float)BDIM);
      if (m >= 1e-3f) accE += Dl[k][ea] * Dl[k][eb];
    }
  }
  if (w == 0) {
    for (int e2 = 0; e2 < 55; ++e2) {
      float vsh = __shfl(accE, e2);
      if (l == 0) {
        int cnt = e2, a2 = 0, b2 = 0;
        for (int q = 0; q < TDIM; ++q) { int row = TDIM - q; if (cnt < row) { a2 = q; b2 = q + cnt; break; } cnt -= row; }
        Mm[a2][b2] = (double)vsh; Mm[b2][a2] = (double)vsh;
      }
    }
  }
  __syncthreads();
  if (tid == 0) {
    for (int sw = 0; sw < 60; ++sw) {
      double off = 0.0;
      for (int a2 = 0; a2 < TDIM; ++a2)
        for (int b2 = a2 + 1; b2 < TDIM; ++b2) off += Mm[a2][b2] * Mm[a2][b2];
      if (off < 1e-22) break;
      for (int a2 = 0; a2 < TDIM - 1; ++a2)
        for (int b2 = a2 + 1; b2 < TDIM; ++b2) {
          double apq = Mm[a2][b2];
          if (fabs(apq) < 1e-30) continue;
          double app = Mm[a2][a2], aqq = Mm[b2][b2];
          double theta = (aqq - app) / (2.0 * apq);
          double tj = (theta >= 0.0 ? 1.0 : -1.0) / (fabs(theta) + sqrt(theta * theta + 1.0));
          double cj = 1.0 / sqrt(tj * tj + 1.0);
          double sj = tj * cj;
          for (int q2 = 0; q2 < TDIM; ++q2) {
            double ap = Mm[a2][q2], aq = Mm[b2][q2];
            Mm[a2][q2] = cj * ap - sj * aq;
            Mm[b2][q2] = sj * ap + cj * aq;
          }
          for (int q2 = 0; q2 < TDIM; ++q2) {
            double ap = Mm[q2][a2], aq = Mm[q2][b2];
            Mm[q2][a2] = cj * ap - sj * aq;
            Mm[q2][b2] = sj * ap + cj * aq;
          }
        }
    }
    float pmin = 3.4e38f; int found = 0;
    for (int a2 = 0; a2 < TDIM; ++a2) {
      float ev = (float)Mm[a2][a2];
      if (ev > 1e-4f) { if (ev < pmin) pmin = ev; found = 1; }
    }
    float pp = found ? pmin : 1.0f;
    float sq = sqrtf(linv * pp);
    bcf[0] = 4.0f * (1.0f - sq) * (1.0f - sq) / (1.0f - pp * linv);
  }
  __syncthreads();
  return bcf[0];
}

// ---------------- k_prep: build D (global) + L (one block) ----------------
__global__ void __launch_bounds__(256)
k_prep(const float* __restrict__ Drr, const float* __restrict__ Dth,
       float* __restrict__ ws) {
  const int tid = threadIdx.x;
  const int w = tid >> 6, l = tid & 63;
  __shared__ float Dl[KDIM][TDIM];
  __shared__ float Msh[64];

  for (int k = tid; k < KDIM; k += 256) {
    int n = k % NPOLE, grp = k / NPOLE;
    float r = Drr[n], th = Dth[n];
    float col[TDIM]; float ss = 0.f, ri = 1.f;
    #pragma unroll
    for (int i = 0; i < TDIM; ++i) {
      float ang = (float)i * th;
      float c = cosf(ang), s = sinf(ang);
      float sgn = (i & 1) ? -1.f : 1.f;
      float v = (grp == 0) ? ri * c : (grp == 1) ? sgn * ri * c
               : (grp == 2) ? ri * s : sgn * ri * s;
      col[i] = v; ss += v * v; ri *= r;
    }
    float G = sqrtf(ss); if (G == 0.f) G = sqrtf((float)TDIM);
    float gi = 1.f / G;
    #pragma unroll
    for (int i = 0; i < TDIM; ++i) {
      Dl[k][i] = col[i] * gi;
      ws[OFF_D + i * KDIM + k] = col[i] * gi;
    }
  }
  __syncthreads();
  for (int e = w; e < 55; e += 4) {
    int cnt = e, t1 = 0, t2 = 0;
    for (int q = 0; q < TDIM; ++q) { int row = TDIM - q; if (cnt < row) { t1 = q; t2 = q + cnt; break; } cnt -= row; }
    float acc = 0.f;
    for (int k = l; k < KDIM; k += 64) acc += Dl[k][t1] * Dl[k][t2];
    #pragma unroll
    for (int o = 32; o > 0; o >>= 1) acc += __shfl_down(acc, o);
    if (l == 0) Msh[e] = acc;
  }
  __syncthreads();
  if (tid == 0) {
    float fro = 0.f; int e = 0;
    for (int t1 = 0; t1 < TDIM; ++t1)
      for (int t2 = t1; t2 < TDIM; ++t2, ++e) {
        float m = Msh[e];
        fro += (t1 == t2 ? 1.f : 2.f) * m * m;
      }
    float linv = 1.f / sqrtf(fro);
    ws[OFF_SC + 0] = linv;
    ws[OFF_SC + 1] = 0.1f * linv;
  }
}

// ---------------- k_iter0: pure iteration 0, no sync ----------------
__global__ void __launch_bounds__(NTI)
k_iter0(const float* __restrict__ Y, float* __restrict__ ws,
        float* __restrict__ out) {
  const int tid = threadIdx.x, blk = blockIdx.x;
  const int ks = blk >> 7, jt = blk & 127;
  const int jl = tid & 31, kg = tid >> 5;
  const int j = jt * JPB + jl, b = j >> 11, p = j & (PDIM - 1);
  const int k0 = ks * (KGI * KPTI) + kg * KPTI;

  __shared__ float Dl[KDIM][TDIM];        // 25.6 KB
  __shared__ float znL[KGI][TDIM][JPB];   // 20.5 KB
  __shared__ float red2[NTI];

  for (int i = tid; i < TDIM * KDIM; i += NTI) {
    int t = i / KDIM, k = i - t * KDIM;
    Dl[k][t] = ws[OFF_D + i];
  }
  const float linv = ws[OFF_SC], lambd = ws[OFF_SC + 1];
  float Yreg[TDIM];
  #pragma unroll
  for (int t = 0; t < TDIM; ++t) Yreg[t] = Y[(b * TDIM + t) * PDIM + p];
  __syncthreads();

  float zn[TDIM];
  #pragma unroll
  for (int t = 0; t < TDIM; ++t) zn[t] = 0.f;
  float cv = 0.f;
  for (int s = 0; s < KPTI; ++s) {
    int k = k0 + s;
    int addr = ((b * KDIM + k) << 11) | p;
    float dt = 0.f;
    #pragma unroll
    for (int t = 0; t < TDIM; ++t) dt += Dl[k][t] * Yreg[t];
    float xv = shrinkf(linv * dt, lambd);
    out[addr] = xv;
    #pragma unroll
    for (int t = 0; t < TDIM; ++t) zn[t] += Dl[k][t] * xv;
    cv += xv * xv;
  }
  #pragma unroll
  for (int t = 0; t < TDIM; ++t) znL[kg][t][jl] = zn[t];
  red2[tid] = cv;
  __syncthreads();
  if (tid < TDIM * JPB) {
    int t = tid >> 5, j2 = tid & 31;
    float s = 0.f;
    #pragma unroll
    for (int g = 0; g < KGI; ++g) s += znL[g][t][j2];
    ws[OFF_U2 + ks * (TDIM * NJ) + t * NJ + jt * JPB + j2] = s;
  }
  for (int o = NTI >> 1; o > 0; o >>= 1) {
    if (tid < o) red2[tid] += red2[tid + o];
    __syncthreads();
  }
  if (tid == 0) {
    ws[OFF_VKP + blk] = -red2[0];   // vk = -||x1||^2 exactly
    ws[OFF_CVP + blk] = red2[0];
  }
}

// ---------------- k_rest: ii=0 control, then iterations 1..99 ----------------
__global__ void __launch_bounds__(NTHR)
k_rest(const float* __restrict__ Y, float* __restrict__ ws,
       float* __restrict__ out) {
  const int tid = threadIdx.x, blk = blockIdx.x;
  const int w = tid >> 6, l = tid & 63;
  const int jl = tid & 31;
  const int kc = tid >> 5;
  const int j = blk * JPB + jl;
  const int b = j >> 11, p = j & (PDIM - 1);
  const int k0 = kc * KPT;
  unsigned long long* slot = (unsigned long long*)(ws + OFF_SLOT);
  unsigned long long* rel  = (unsigned long long*)(ws + OFF_REL);

  __shared__ float Dl[KDIM][TDIM];
  __shared__ float znL[KCH][TDIM][JPB];
  __shared__ float uL[2][TDIM][JPB];
  __shared__ float red[NTHR], red2[NTHR];
  __shared__ float csum[KDIM];
  __shared__ double Mm[TDIM][TDIM];
  __shared__ float vkbufL[MAXIT];
  __shared__ float bcf[4];

  for (int i = tid; i < TDIM * KDIM; i += NTHR) {
    int t = i / KDIM, k = i - t * KDIM;
    Dl[k][t] = ws[OFF_D + i];
  }
  const float linv = ws[OFF_SC], lambd = ws[OFF_SC + 1];
  __syncthreads();

  float* wsX = ws + OFF_XB;
  float tt = 0.f;
  int relcnt = 0, lastii = MAXIT - 1, dn0 = 0;
  float st_t = 1.f, st_r = 4.f;
  int oscF = 1, oscS = 0, kpos = 0, gap_ = 0;

  // ---- entry: scalar/control update for ii = 0 (partials from k_iter0) ----
  if (blk == 0) {
    red[tid]  = ws[OFF_VKP + tid];
    red2[tid] = ws[OFF_CVP + tid];
    __syncthreads();
    for (int o = NTHR >> 1; o > 0; o >>= 1) {
      if (tid < o) { red[tid] += red[tid + o]; red2[tid] += red2[tid + o]; }
      __syncthreads();
    }
    float vkt = red[0], cvt = red2[0];
    if (tid == 0) vkbufL[0] = vkt;
    __syncthreads();
    int cond1 = oscF && (vkt >= 0.f);
    float r_alpha = 0.f;
    if (cond1) r_alpha = alpha_eval(out, Dl, csum, Mm, bcf, linv, w, l, tid);
    float r1 = (r_alpha == 4.0f) ? 3.99f : r_alpha;
    float r_new = cond1 ? r1 : st_r;
    float t_cur = cond1 ? (4.0f / (4.0f - r1) / 1.1f) : st_t;
    kpos = cond1 ? 10 : kpos;
    gap_ = cond1 ? 0 : gap_;
    oscF = oscF && !cond1;
    oscS = cond1 ? 1 : oscS;
    float t_next = (1.f + sqrtf(1.f + r_new * t_cur * t_cur)) * 0.5f;
    float tt_new = (t_cur - 1.f) / t_next;
    float conv = sqrtf(cvt) / (float)PDIM;
    st_t = t_next; st_r = r_new;
    int done = (conv < 0.01f) ? 1 : 0;
    relcnt = 1;
    if (tid == 0) {
      unsigned long long wv =
          ((unsigned long long)__float_as_uint(tt_new) << 32)
        | (1ULL << 3) | (unsigned long long)done;
      __hip_atomic_store(rel, wv, __ATOMIC_RELEASE, __HIP_MEMORY_SCOPE_AGENT);
    }
    tt = tt_new; dn0 = done;
  } else {
    if (tid == 0) {
      unsigned long long wv; int g = 0;
      for (;;) {
        wv = __hip_atomic_load(rel, __ATOMIC_RELAXED, __HIP_MEMORY_SCOPE_AGENT);
        if (SEQ(wv) >= 1) break;
        __builtin_amdgcn_s_sleep(4);
        if (++g > (1 << 22)) break;
      }
      bcf[0] = __uint_as_float((unsigned)(wv >> 32));
      bcf[1] = (float)DONE(wv);
    }
    __syncthreads();
    tt = bcf[0]; dn0 = (bcf[1] != 0.f);
    relcnt = 1;
    __syncthreads();
  }

  if (dn0) { lastii = 0; }
  else {
    float Yreg[TDIM];
    #pragma unroll
    for (int t = 0; t < TDIM; ++t) Yreg[t] = Y[(b * TDIM + t) * PDIM + p];
    for (int i = tid; i < TDIM * JPB; i += NTHR) {
      int t = i >> 5, j2 = i & 31;
      uL[0][t][j2] = ws[OFF_U2 + t * NJ + blk * JPB + j2]
                   + ws[OFF_U2 + TDIM * NJ + t * NJ + blk * JPB + j2];
    }
    __syncthreads();

    for (int ii = 1; ii < MAXIT; ++ii) {
      const int pz = (ii <= 1);
      const int pr = ii & 1;
      float*       xnw  = pr ? wsX : out;
      const float* xcur = pr ? out : wsX;
      const float om = 1.f + tt;

      float zj[TDIM];
      #pragma unroll
      for (int t = 0; t < TDIM; ++t) {
        float a  = uL[pr ^ 1][t][jl];
        float bb = pz ? 0.f : uL[pr][t][jl];
        zj[t] = om * a - tt * bb;
      }
      float zn[TDIM];
      #pragma unroll
      for (int t = 0; t < TDIM; ++t) zn[t] = 0.f;
      float vk = 0.f, cv = 0.f;

      for (int s = 0; s < KPT; ++s) {
        int k = k0 + s;
        int addr = ((b * KDIM + k) << 11) | p;
        float xcv = xcur[addr];
        float xov = pz ? 0.f : xnw[addr];
        float y   = om * xcv - tt * xov;
        float wd = 0.f, dt = 0.f;
        #pragma unroll
        for (int t = 0; t < TDIM; ++t) { wd += Dl[k][t] * zj[t]; dt += Dl[k][t] * Yreg[t]; }
        float v = y + linv * (dt - wd);
        float xv = shrinkf(v, lambd);
        xnw[addr] = xv;
        #pragma unroll
        for (int t = 0; t < TDIM; ++t) zn[t] += Dl[k][t] * xv;
        vk += (y - xv) * (xv - xcv);
        float d = xv - xcv; cv += d * d;
      }

      #pragma unroll
      for (int t = 0; t < TDIM; ++t) znL[kc][t][jl] = zn[t];
      red[tid] = vk; red2[tid] = cv;
      __syncthreads();
      for (int i = tid; i < TDIM * JPB; i += NTHR) {
        int t = i >> 5, j2 = i & 31;
        float s = 0.f;
        #pragma unroll
        for (int c = 0; c < KCH; ++c) s += znL[c][t][j2];
        uL[pr][t][j2] = s;
      }
      for (int o = NTHR >> 1; o > 0; o >>= 1) {
        if (tid < o) { red[tid] += red[tid + o]; red2[tid] += red2[tid + o]; }
        __syncthreads();
      }
      if (tid == 0) {
        unsigned long long pay =
            ((unsigned long long)__float_as_uint(red2[0] + 1.0f) << 32)
          | (unsigned long long)__float_as_uint(red[0]);
        __hip_atomic_store(&slot[pr * NBLK + blk], pay, __ATOMIC_RELAXED, __HIP_MEMORY_SCOPE_AGENT);
      }

      if (blk == 0) {
        float pvk = 0.f, pcv = 0.f;
        if (tid < NBLK) {
          unsigned long long v; int g = 0;
          for (;;) {
            v = __hip_atomic_load(&slot[pr * NBLK + tid], __ATOMIC_RELAXED, __HIP_MEMORY_SCOPE_AGENT);
            if ((unsigned)(v >> 32) != 0u) break;
            __builtin_amdgcn_s_sleep(4);
            if (++g > (1 << 22)) break;
          }
          pvk = __uint_as_float((unsigned)v);
          pcv = __uint_as_float((unsigned)(v >> 32)) - 1.0f;
          __hip_atomic_store(&slot[pr * NBLK + tid], 0ULL, __ATOMIC_RELAXED, __HIP_MEMORY_SCOPE_AGENT);
        }
        red[tid] = pvk; red2[tid] = pcv;
        __syncthreads();
        for (int o = NTHR >> 1; o > 0; o >>= 1) {
          if (tid < o) { red[tid] += red[tid + o]; red2[tid] += red2[tid + o]; }
          __syncthreads();
        }
        float vkt = red[0], cvt = red2[0];
        if (tid == 0) vkbufL[ii] = vkt;
        __syncthreads();

        int cond1 = oscF && (vkt >= 0.f);
        int Lg = ii - kpos;
        float sum_k = 0.f;
        if (Lg >= 3) {
          int i1 = ii - 1;   i1 = i1 < 0 ? 0 : (i1 > MAXIT - 1 ? MAXIT - 1 : i1);
          int i2 = kpos + 1; i2 = i2 < 0 ? 0 : (i2 > MAXIT - 1 ? MAXIT - 1 : i2);
          sum_k = sgnf(vkbufL[i1]) - sgnf(vkbufL[i2]);
        }
        int cond2 = oscS && (vkt <= 0.f) && (Lg >= 2 * gap_) && (sum_k == 0.f);

        float r_alpha = 0.f;
        if (cond1 || cond2) {
          // flush protocol so block 0 can read remote x_new
          ++relcnt;
          if (tid == 0) {
            unsigned long long wv = ((unsigned long long)(unsigned)relcnt << 3) | 4ULL;
            __hip_atomic_store(rel, wv, __ATOMIC_RELEASE, __HIP_MEMORY_SCOPE_AGENT);
            __hip_atomic_store(&slot[(pr ^ 1) * NBLK + 0], 1ULL << 32, __ATOMIC_RELAXED, __HIP_MEMORY_SCOPE_AGENT);
          }
          if (tid < NBLK) {
            int g = 0;
            while ((unsigned)(__hip_atomic_load(&slot[(pr ^ 1) * NBLK + tid], __ATOMIC_RELAXED,
                                                __HIP_MEMORY_SCOPE_AGENT) >> 32) == 0u) {
              __builtin_amdgcn_s_sleep(4);
              if (++g > (1 << 22)) break;
            }
          }
          __syncthreads();
          if (tid == 0) __threadfence();
          __syncthreads();
          if (tid < NBLK)
            __hip_atomic_store(&slot[(pr ^ 1) * NBLK + tid], 0ULL, __ATOMIC_RELAXED, __HIP_MEMORY_SCOPE_AGENT);
          r_alpha = alpha_eval(pr ? wsX : out, Dl, csum, Mm, bcf, linv, w, l, tid);
        }

        float r1 = (r_alpha == 4.0f) ? 3.99f : r_alpha;
        float r_new = cond1 ? r1 : (cond2 ? r_alpha : st_r);
        float t_cur = cond1 ? (4.0f / (4.0f - r1) / 1.1f) : st_t;
        kpos = cond1 ? (ii + 10) : kpos;
        gap_ = cond1 ? ii : gap_;
        oscF = oscF && !cond1;
        oscS = cond1 ? 1 : (oscS && !cond2);
        float t_next = (1.f + sqrtf(1.f + r_new * t_cur * t_cur)) * 0.5f;
        float tt_new = (t_cur - 1.f) / t_next;
        float conv = sqrtf(cvt) / (float)KDIM;
        st_t = t_next; st_r = r_new;
        int done = (conv < 0.01f) ? 1 : 0;
        ++relcnt;
        if (tid == 0) {
          unsigned long long wv =
              ((unsigned long long)__float_as_uint(tt_new) << 32)
            | ((unsigned long long)(unsigned)relcnt << 3) | (unsigned long long)done;
          __hip_atomic_store(rel, wv, __ATOMIC_RELEASE, __HIP_MEMORY_SCOPE_AGENT);
        }
        tt = tt_new;
        if (done) { lastii = ii; break; }
      } else {
        if (tid == 0) {
          int exps = relcnt + 1;
          for (;;) {
            unsigned long long wv; int g = 0;
            for (;;) {
              wv = __hip_atomic_load(rel, __ATOMIC_RELAXED, __HIP_MEMORY_SCOPE_AGENT);
              if (SEQ(wv) >= exps) break;
              __builtin_amdgcn_s_sleep(4);
              if (++g > (1 << 22)) break;
            }
            if (FLUSH(wv) && SEQ(wv) == exps) {
              __threadfence();
              __hip_atomic_store(&slot[(pr ^ 1) * NBLK + blk], 1ULL << 32,
                                 __ATOMIC_RELAXED, __HIP_MEMORY_SCOPE_AGENT);
              ++exps;
              continue;
            }
            relcnt = exps;
            bcf[0] = __uint_as_float((unsigned)(wv >> 32));
            bcf[1] = (float)DONE(wv);
            break;
          }
        }
        __syncthreads();
        tt = bcf[0];
        float dn = bcf[1];
        __syncthreads();
        if (dn != 0.f) { lastii = ii; break; }
      }
    }
  }

  // final x parity: odd lastii -> copy own region wsX -> out
  if (lastii & 1) {
    for (int s = 0; s < KPT; ++s) {
      int k = k0 + s;
      int addr = ((b * KDIM + k) << 11) | p;
      out[addr] = wsX[addr];
    }
  }
}

extern "C" void kernel_launch(void* const* d_in, const int* in_sizes, int n_in,
                              void* d_out, int out_size, void* d_ws, size_t ws_size,
                              hipStream_t stream) {
  (void)in_sizes; (void)n_in; (void)out_size;
  if (ws_size < (size_t)WS_FLOATS * 4) return;
  const float* Y   = (const float*)d_in[0];
  const float* Drr = (const float*)d_in[1];
  const float* Dth = (const float*)d_in[2];
  float* out = (float*)d_out;
  float* ws  = (float*)d_ws;

  hipMemsetAsync(ws, 0, MEMSET_BYTES, stream);
  hipLaunchKernelGGL(k_prep, dim3(1), dim3(256), 0, stream, Drr, Dth, ws);
  hipLaunchKernelGGL(k_iter0, dim3(NBI), dim3(NTI), 0, stream, Y, ws, out);
  hipLaunchKernelGGL(k_rest, dim3(NBLK), dim3(NTHR), 0, stream, Y, ws, out);
}

// Round 8
// 22.571 us; speedup vs baseline: 9.5997x; 1.8378x over previous
//
#include <hip/hip_runtime.h>

#define NPOLE 160
#define KDIM  640
#define TDIM  10
#define PDIM  2048
#define BDIM  2
#define NJ    4096            // BDIM*PDIM
#define MAXIT 100

// ---- k_iter0 geometry: 256 blocks x 512 threads ----
#define NBI   256
#define NTI   512
#define KGI   16              // k-groups per block
#define KPTI  20              // k per thread
// ---- k_rest geometry ----
#define NBLK  128
#define NTHR  256
#define JPB   32
#define KCH   8
#define KPT   80

// ws float offsets (no memset; header zeroed by k_iter0 blk0)
#define OFF_SLOT 0            // u64 slot[2][NBLK] = 512 floats
#define OFF_REL  512          // u64 release word (own cache line)
#define OFF_HDR  576          // floats zeroed each launch
#define OFF_VKP  576          // 256 vk partials
#define OFF_CVP  832          // 256 cv partials
#define OFF_U2   1088         // 2 x 40960 per-ks u partials
#define OFF_XB   83008        // 2621440 x ping-pong partner of d_out
#define WS_FLOATS (OFF_XB + BDIM*KDIM*PDIM)   // 10.82 MB

#define SEQ(wv)   ((int)(((wv) >> 3) & 0x1FFFFFFF))
#define FLUSH(wv) ((int)(((wv) >> 2) & 1))
#define DONE(wv)  ((int)((wv) & 1))

__device__ __forceinline__ float sgnf(float x) {
  return (x > 0.f) ? 1.f : ((x < 0.f) ? -1.f : 0.f);
}
__device__ __forceinline__ float shrinkf(float v, float lam) {
  return (v > lam) ? v - lam : ((v < -lam) ? v + lam : 0.f);
}

// build normalized dictionary into LDS + L = ||DtD||_F via 10x10 DD^T identity
template <int NT>
__device__ void build_D_L(const float* __restrict__ Drr, const float* __restrict__ Dth,
                          float (*Dl)[TDIM], float* Msh, float& linv, float& lambd) {
  const int tid = threadIdx.x, w = tid >> 6, l = tid & 63;
  for (int k = tid; k < KDIM; k += NT) {
    int n = k % NPOLE, grp = k / NPOLE;
    float r = Drr[n], th = Dth[n];
    float col[TDIM]; float ss = 0.f, ri = 1.f;
    #pragma unroll
    for (int i = 0; i < TDIM; ++i) {
      float ang = (float)i * th;
      float c = cosf(ang), s = sinf(ang);
      float sgn = (i & 1) ? -1.f : 1.f;
      float v = (grp == 0) ? ri * c : (grp == 1) ? sgn * ri * c
               : (grp == 2) ? ri * s : sgn * ri * s;
      col[i] = v; ss += v * v; ri *= r;
    }
    float G = sqrtf(ss); if (G == 0.f) G = sqrtf((float)TDIM);
    float gi = 1.f / G;
    #pragma unroll
    for (int i = 0; i < TDIM; ++i) Dl[k][i] = col[i] * gi;
  }
  __syncthreads();
  const int NW = NT / 64;
  for (int e = w; e < 55; e += NW) {
    int cnt = e, t1 = 0, t2 = 0;
    for (int q = 0; q < TDIM; ++q) { int row = TDIM - q; if (cnt < row) { t1 = q; t2 = q + cnt; break; } cnt -= row; }
    float acc = 0.f;
    for (int k = l; k < KDIM; k += 64) acc += Dl[k][t1] * Dl[k][t2];
    #pragma unroll
    for (int o = 32; o > 0; o >>= 1) acc += __shfl_down(acc, o);
    if (l == 0) Msh[e] = acc;
  }
  __syncthreads();
  float fro = 0.f;
  {
    int e = 0;
    for (int t1 = 0; t1 < TDIM; ++t1)
      for (int t2 = t1; t2 < TDIM; ++t2, ++e) {
        float m = Msh[e];
        fro += (t1 == t2 ? 1.f : 2.f) * m * m;
      }
  }
  linv = 1.f / sqrtf(fro);
  lambd = 0.1f * linv;
}

// masked-dictionary alpha (block-uniform call; 4-wave blocks)
__device__ float alpha_eval(const float* __restrict__ xn, const float (*Dl)[TDIM],
                            float* csum, double (*Mm)[TDIM], float* bcf,
                            float linv, int w, int l, int tid) {
  for (int k = w; k < KDIM; k += 4) {
    float acc = 0.f;
    for (int idx = l; idx < NJ; idx += 64) {
      int b2 = idx >> 11, p2 = idx & (PDIM - 1);
      acc += xn[((b2 * KDIM + k) << 11) | p2];
    }
    #pragma unroll
    for (int o = 32; o > 0; o >>= 1) acc += __shfl_down(acc, o);
    if (l == 0) csum[k] = acc;
  }
  __syncthreads();
  float accE = 0.f;
  if (tid < 55) {
    int cnt = tid, ea = 0, eb = 0;
    for (int q = 0; q < TDIM; ++q) { int row = TDIM - q; if (cnt < row) { ea = q; eb = q + cnt; break; } cnt -= row; }
    for (int k = 0; k < KDIM; ++k) {
      float m = fabsf(csum[k] / (float)PDIM / (float)BDIM);
      if (m >= 1e-3f) accE += Dl[k][ea] * Dl[k][eb];
    }
  }
  if (w == 0) {
    for (int e2 = 0; e2 < 55; ++e2) {
      float vsh = __shfl(accE, e2);
      if (l == 0) {
        int cnt = e2, a2 = 0, b2 = 0;
        for (int q = 0; q < TDIM; ++q) { int row = TDIM - q; if (cnt < row) { a2 = q; b2 = q + cnt; break; } cnt -= row; }
        Mm[a2][b2] = (double)vsh; Mm[b2][a2] = (double)vsh;
      }
    }
  }
  __syncthreads();
  if (tid == 0) {
    for (int sw = 0; sw < 60; ++sw) {
      double off = 0.0;
      for (int a2 = 0; a2 < TDIM; ++a2)
        for (int b2 = a2 + 1; b2 < TDIM; ++b2) off += Mm[a2][b2] * Mm[a2][b2];
      if (off < 1e-22) break;
      for (int a2 = 0; a2 < TDIM - 1; ++a2)
        for (int b2 = a2 + 1; b2 < TDIM; ++b2) {
          double apq = Mm[a2][b2];
          if (fabs(apq) < 1e-30) continue;
          double app = Mm[a2][a2], aqq = Mm[b2][b2];
          double theta = (aqq - app) / (2.0 * apq);
          double tj = (theta >= 0.0 ? 1.0 : -1.0) / (fabs(theta) + sqrt(theta * theta + 1.0));
          double cj = 1.0 / sqrt(tj * tj + 1.0);
          double sj = tj * cj;
          for (int q2 = 0; q2 < TDIM; ++q2) {
            double ap = Mm[a2][q2], aq = Mm[b2][q2];
            Mm[a2][q2] = cj * ap - sj * aq;
            Mm[b2][q2] = sj * ap + cj * aq;
          }
          for (int q2 = 0; q2 < TDIM; ++q2) {
            double ap = Mm[q2][a2], aq = Mm[q2][b2];
            Mm[q2][a2] = cj * ap - sj * aq;
            Mm[q2][b2] = sj * ap + cj * aq;
          }
        }
    }
    float pmin = 3.4e38f; int found = 0;
    for (int a2 = 0; a2 < TDIM; ++a2) {
      float ev = (float)Mm[a2][a2];
      if (ev > 1e-4f) { if (ev < pmin) pmin = ev; found = 1; }
    }
    float pp = found ? pmin : 1.0f;
    float sq = sqrtf(linv * pp);
    bcf[0] = 4.0f * (1.0f - sq) * (1.0f - sq) / (1.0f - pp * linv);
  }
  __syncthreads();
  return bcf[0];
}

// ---------------- k_iter0: D+L build, iteration 0, partials, header zero ----
__global__ void __launch_bounds__(NTI)
k_iter0(const float* __restrict__ Y, const float* __restrict__ Drr,
        const float* __restrict__ Dth, float* __restrict__ ws,
        float* __restrict__ out) {
  const int tid = threadIdx.x, blk = blockIdx.x;
  const int w = tid >> 6, l = tid & 63;
  const int ks = blk >> 7, jt = blk & 127;
  const int jl = tid & 31, kg = tid >> 5;
  const int j = jt * JPB + jl, b = j >> 11, p = j & (PDIM - 1);
  const int k0 = ks * (KGI * KPTI) + kg * KPTI;

  __shared__ float Dl[KDIM][TDIM];        // 25.6 KB
  __shared__ float znL[KGI][TDIM][JPB];   // 20.5 KB
  __shared__ float Msh[64];
  __shared__ float redc[8];

  if (blk == 0)   // zero sync header for k_rest (visible at dispatch boundary)
    for (int i = tid; i < OFF_HDR; i += NTI) ws[i] = 0.f;

  float linv, lambd;
  build_D_L<NTI>(Drr, Dth, Dl, Msh, linv, lambd);

  float Yreg[TDIM];
  #pragma unroll
  for (int t = 0; t < TDIM; ++t) Yreg[t] = Y[(b * TDIM + t) * PDIM + p];

  float zn[TDIM];
  #pragma unroll
  for (int t = 0; t < TDIM; ++t) zn[t] = 0.f;
  float cv = 0.f;
  for (int s = 0; s < KPTI; ++s) {
    int k = k0 + s;
    int addr = ((b * KDIM + k) << 11) | p;
    float dt = 0.f;
    #pragma unroll
    for (int t = 0; t < TDIM; ++t) dt += Dl[k][t] * Yreg[t];
    float xv = shrinkf(linv * dt, lambd);
    out[addr] = xv;
    #pragma unroll
    for (int t = 0; t < TDIM; ++t) zn[t] += Dl[k][t] * xv;
    cv += xv * xv;
  }
  #pragma unroll
  for (int t = 0; t < TDIM; ++t) znL[kg][t][jl] = zn[t];
  __syncthreads();
  if (tid < TDIM * JPB) {                  // u partials for this (ks, jt)
    int t = tid >> 5, j2 = tid & 31;
    float s = 0.f;
    #pragma unroll
    for (int g = 0; g < KGI; ++g) s += znL[g][t][j2];
    ws[OFF_U2 + ks * (TDIM * NJ) + t * NJ + jt * JPB + j2] = s;
  }
  // cv reduce: wave shuffle + 8-leader LDS
  #pragma unroll
  for (int o = 32; o > 0; o >>= 1) cv += __shfl_down(cv, o);
  if (l == 0) redc[w] = cv;
  __syncthreads();
  if (tid == 0) {
    float s = 0.f;
    #pragma unroll
    for (int q = 0; q < 8; ++q) s += redc[q];
    ws[OFF_VKP + blk] = -s;                // vk(ii=0) = -||x1||^2 exactly
    ws[OFF_CVP + blk] = s;
  }
}

// ---------------- k_rest: redundant entry control; loop only if needed ------
__global__ void __launch_bounds__(NTHR)
k_rest(const float* __restrict__ Y, const float* __restrict__ Drr,
       const float* __restrict__ Dth, float* __restrict__ ws,
       float* __restrict__ out) {
  const int tid = threadIdx.x, blk = blockIdx.x;
  const int w = tid >> 6, l = tid & 63;
  const int jl = tid & 31, kc = tid >> 5;
  const int j = blk * JPB + jl;
  const int b = j >> 11, p = j & (PDIM - 1);
  const int k0 = kc * KPT;
  unsigned long long* slot = (unsigned long long*)(ws + OFF_SLOT);
  unsigned long long* rel  = (unsigned long long*)(ws + OFF_REL);

  __shared__ float red[NTHR], red2[NTHR];

  // ---- entry: every block redundantly reduces the 256 partials ----
  red[tid]  = ws[OFF_VKP + tid];
  red2[tid] = ws[OFF_CVP + tid];
  __syncthreads();
  for (int o = NTHR >> 1; o > 0; o >>= 1) {
    if (tid < o) { red[tid] += red[tid + o]; red2[tid] += red2[tid + o]; }
    __syncthreads();
  }
  const float vkt0 = red[0], cvt0 = red2[0];
  if (sqrtf(cvt0) / (float)PDIM < 0.01f) return;   // converged at ii=0 (common)

  // ---- not converged: full state + loop ----
  __shared__ float Dl[KDIM][TDIM];
  __shared__ float znL[KCH][TDIM][JPB];
  __shared__ float uL[2][TDIM][JPB];
  __shared__ float csum[KDIM];
  __shared__ float Msh[64];
  __shared__ double Mm[TDIM][TDIM];
  __shared__ float vkbufL[MAXIT];
  __shared__ float bcf[4];

  float linv, lambd;
  build_D_L<NTHR>(Drr, Dth, Dl, Msh, linv, lambd);

  float Yreg[TDIM];
  #pragma unroll
  for (int t = 0; t < TDIM; ++t) Yreg[t] = Y[(b * TDIM + t) * PDIM + p];
  for (int i = tid; i < TDIM * JPB; i += NTHR) {
    int t = i >> 5, j2 = i & 31;
    uL[0][t][j2] = ws[OFF_U2 + t * NJ + blk * JPB + j2]
                 + ws[OFF_U2 + TDIM * NJ + t * NJ + blk * JPB + j2];
  }
  if (tid == 0) vkbufL[0] = vkt0;
  __syncthreads();

  // entry control, redundant per block (bit-identical everywhere)
  float st_t = 1.f, st_r = 4.f;
  int oscF = 1, oscS = 0, kpos = 0, gap_ = 0;
  {
    int cond1 = (vkt0 >= 0.f);
    float r_alpha = 0.f;
    if (cond1) r_alpha = alpha_eval(out, Dl, csum, Mm, bcf, linv, w, l, tid);
    float r1 = (r_alpha == 4.0f) ? 3.99f : r_alpha;
    float r_new = cond1 ? r1 : st_r;
    float t_cur = cond1 ? (4.0f / (4.0f - r1) / 1.1f) : st_t;
    kpos = cond1 ? 10 : kpos;
    gap_ = cond1 ? 0 : gap_;
    oscF = oscF && !cond1;
    oscS = cond1 ? 1 : oscS;
    float t_next = (1.f + sqrtf(1.f + r_new * t_cur * t_cur)) * 0.5f;
    st_t = t_next; st_r = r_new;
  }
  float tt = (st_t == 0.f) ? 0.f : 0.f;  // placeholder; real tt below
  tt = ( ( (vkt0 >= 0.f) ? (4.0f / (4.0f - ((st_r == 4.0f) ? 3.99f : st_r)) / 1.1f) : 1.f ) - 1.f) / st_t;
  // recompute cleanly (avoid any ambiguity): tt = (t_cur - 1)/t_next with the values used above
  {
    int cond1 = (vkt0 >= 0.f);
    float r_alpha_used = cond1 ? ((st_r == 4.0f) ? 4.0f : st_r) : 4.f; (void)r_alpha_used;
    float r1 = (st_r == 4.0f) ? 3.99f : st_r;          // st_r holds r_new
    float t_cur = cond1 ? (4.0f / (4.0f - r1) / 1.1f) : 1.f;
    tt = (t_cur - 1.f) / st_t;
  }

  float* wsX = ws + OFF_XB;
  int relcnt = 0, lastii = MAXIT - 1;

  for (int ii = 1; ii < MAXIT; ++ii) {
    const int pz = (ii <= 1);
    const int pr = ii & 1;
    float*       xnw  = pr ? wsX : out;
    const float* xcur = pr ? out : wsX;
    const float om = 1.f + tt;

    float zj[TDIM];
    #pragma unroll
    for (int t = 0; t < TDIM; ++t) {
      float a  = uL[pr ^ 1][t][jl];
      float bb = pz ? 0.f : uL[pr][t][jl];
      zj[t] = om * a - tt * bb;
    }
    float zn[TDIM];
    #pragma unroll
    for (int t = 0; t < TDIM; ++t) zn[t] = 0.f;
    float vk = 0.f, cv = 0.f;

    for (int s = 0; s < KPT; ++s) {
      int k = k0 + s;
      int addr = ((b * KDIM + k) << 11) | p;
      float xcv = xcur[addr];
      float xov = pz ? 0.f : xnw[addr];
      float y   = om * xcv - tt * xov;
      float wd = 0.f, dt = 0.f;
      #pragma unroll
      for (int t = 0; t < TDIM; ++t) { wd += Dl[k][t] * zj[t]; dt += Dl[k][t] * Yreg[t]; }
      float v = y + linv * (dt - wd);
      float xv = shrinkf(v, lambd);
      xnw[addr] = xv;
      #pragma unroll
      for (int t = 0; t < TDIM; ++t) zn[t] += Dl[k][t] * xv;
      vk += (y - xv) * (xv - xcv);
      float d = xv - xcv; cv += d * d;
    }

    #pragma unroll
    for (int t = 0; t < TDIM; ++t) znL[kc][t][jl] = zn[t];
    red[tid] = vk; red2[tid] = cv;
    __syncthreads();
    for (int i = tid; i < TDIM * JPB; i += NTHR) {
      int t = i >> 5, j2 = i & 31;
      float s = 0.f;
      #pragma unroll
      for (int c = 0; c < KCH; ++c) s += znL[c][t][j2];
      uL[pr][t][j2] = s;
    }
    for (int o = NTHR >> 1; o > 0; o >>= 1) {
      if (tid < o) { red[tid] += red[tid + o]; red2[tid] += red2[tid + o]; }
      __syncthreads();
    }
    if (tid == 0) {
      unsigned long long pay =
          ((unsigned long long)__float_as_uint(red2[0] + 1.0f) << 32)
        | (unsigned long long)__float_as_uint(red[0]);
      __hip_atomic_store(&slot[pr * NBLK + blk], pay, __ATOMIC_RELAXED, __HIP_MEMORY_SCOPE_AGENT);
    }

    if (blk == 0) {
      float pvk = 0.f, pcv = 0.f;
      if (tid < NBLK) {
        unsigned long long v; int g = 0;
        for (;;) {
          v = __hip_atomic_load(&slot[pr * NBLK + tid], __ATOMIC_RELAXED, __HIP_MEMORY_SCOPE_AGENT);
          if ((unsigned)(v >> 32) != 0u) break;
          __builtin_amdgcn_s_sleep(4);
          if (++g > (1 << 22)) break;
        }
        pvk = __uint_as_float((unsigned)v);
        pcv = __uint_as_float((unsigned)(v >> 32)) - 1.0f;
        __hip_atomic_store(&slot[pr * NBLK + tid], 0ULL, __ATOMIC_RELAXED, __HIP_MEMORY_SCOPE_AGENT);
      }
      red[tid] = pvk; red2[tid] = pcv;
      __syncthreads();
      for (int o = NTHR >> 1; o > 0; o >>= 1) {
        if (tid < o) { red[tid] += red[tid + o]; red2[tid] += red2[tid + o]; }
        __syncthreads();
      }
      float vkt = red[0], cvt = red2[0];
      if (tid == 0) vkbufL[ii] = vkt;
      __syncthreads();

      int cond1 = oscF && (vkt >= 0.f);
      int Lg = ii - kpos;
      float sum_k = 0.f;
      if (Lg >= 3) {
        int i1 = ii - 1;   i1 = i1 < 0 ? 0 : (i1 > MAXIT - 1 ? MAXIT - 1 : i1);
        int i2 = kpos + 1; i2 = i2 < 0 ? 0 : (i2 > MAXIT - 1 ? MAXIT - 1 : i2);
        sum_k = sgnf(vkbufL[i1]) - sgnf(vkbufL[i2]);
      }
      int cond2 = oscS && (vkt <= 0.f) && (Lg >= 2 * gap_) && (sum_k == 0.f);

      float r_alpha = 0.f;
      if (cond1 || cond2) {
        ++relcnt;      // flush protocol for cross-block x visibility
        if (tid == 0) {
          unsigned long long wv = ((unsigned long long)(unsigned)relcnt << 3) | 4ULL;
          __hip_atomic_store(rel, wv, __ATOMIC_RELEASE, __HIP_MEMORY_SCOPE_AGENT);
          __hip_atomic_store(&slot[(pr ^ 1) * NBLK + 0], 1ULL << 32, __ATOMIC_RELAXED, __HIP_MEMORY_SCOPE_AGENT);
        }
        if (tid < NBLK) {
          int g = 0;
          while ((unsigned)(__hip_atomic_load(&slot[(pr ^ 1) * NBLK + tid], __ATOMIC_RELAXED,
                                              __HIP_MEMORY_SCOPE_AGENT) >> 32) == 0u) {
            __builtin_amdgcn_s_sleep(4);
            if (++g > (1 << 22)) break;
          }
        }
        __syncthreads();
        if (tid == 0) __threadfence();
        __syncthreads();
        if (tid < NBLK)
          __hip_atomic_store(&slot[(pr ^ 1) * NBLK + tid], 0ULL, __ATOMIC_RELAXED, __HIP_MEMORY_SCOPE_AGENT);
        r_alpha = alpha_eval(pr ? wsX : out, Dl, csum, Mm, bcf, linv, w, l, tid);
      }

      float r1 = (r_alpha == 4.0f) ? 3.99f : r_alpha;
      float r_new = cond1 ? r1 : (cond2 ? r_alpha : st_r);
      float t_cur = cond1 ? (4.0f / (4.0f - r1) / 1.1f) : st_t;
      kpos = cond1 ? (ii + 10) : kpos;
      gap_ = cond1 ? ii : gap_;
      oscF = oscF && !cond1;
      oscS = cond1 ? 1 : (oscS && !cond2);
      float t_next = (1.f + sqrtf(1.f + r_new * t_cur * t_cur)) * 0.5f;
      float tt_new = (t_cur - 1.f) / t_next;
      float conv = sqrtf(cvt) / (float)KDIM;
      st_t = t_next; st_r = r_new;
      int done = (conv < 0.01f) ? 1 : 0;
      ++relcnt;
      if (tid == 0) {
        unsigned long long wv =
            ((unsigned long long)__float_as_uint(tt_new) << 32)
          | ((unsigned long long)(unsigned)relcnt << 3) | (unsigned long long)done;
        __hip_atomic_store(rel, wv, __ATOMIC_RELEASE, __HIP_MEMORY_SCOPE_AGENT);
      }
      tt = tt_new;
      if (done) { lastii = ii; break; }
    } else {
      if (tid == 0) {
        int exps = relcnt + 1;
        for (;;) {
          unsigned long long wv; int g = 0;
          for (;;) {
            wv = __hip_atomic_load(rel, __ATOMIC_RELAXED, __HIP_MEMORY_SCOPE_AGENT);
            if (SEQ(wv) >= exps) break;
            __builtin_amdgcn_s_sleep(4);
            if (++g > (1 << 22)) break;
          }
          if (FLUSH(wv) && SEQ(wv) == exps) {
            __threadfence();
            __hip_atomic_store(&slot[(pr ^ 1) * NBLK + blk], 1ULL << 32,
                               __ATOMIC_RELAXED, __HIP_MEMORY_SCOPE_AGENT);
            ++exps;
            continue;
          }
          relcnt = exps;
          bcf[0] = __uint_as_float((unsigned)(wv >> 32));
          bcf[1] = (float)DONE(wv);
          break;
        }
      }
      __syncthreads();
      tt = bcf[0];
      float dn = bcf[1];
      __syncthreads();
      if (dn != 0.f) { lastii = ii; break; }
    }
  }

  // final x parity: odd lastii -> copy own region wsX -> out
  if (lastii & 1) {
    for (int s = 0; s < KPT; ++s) {
      int k = k0 + s;
      int addr = ((b * KDIM + k) << 11) | p;
      out[addr] = wsX[addr];
    }
  }
}

extern "C" void kernel_launch(void* const* d_in, const int* in_sizes, int n_in,
                              void* d_out, int out_size, void* d_ws, size_t ws_size,
                              hipStream_t stream) {
  (void)in_sizes; (void)n_in; (void)out_size;
  if (ws_size < (size_t)WS_FLOATS * 4) return;
  const float* Y   = (const float*)d_in[0];
  const float* Drr = (const float*)d_in[1];
  const float* Dth = (const float*)d_in[2];
  float* out = (float*)d_out;
  float* ws  = (float*)d_ws;

  hipLaunchKernelGGL(k_iter0, dim3(NBI), dim3(NTI), 0, stream, Y, Drr, Dth, ws, out);
  hipLaunchKernelGGL(k_rest, dim3(NBLK), dim3(NTHR), 0, stream, Y, Drr, Dth, ws, out);
}

// Round 9
// 21.520 us; speedup vs baseline: 10.0685x; 1.0488x over previous
//
#include <hip/hip_runtime.h>

#define NPOLE 160
#define KDIM  640
#define TDIM  10
#define PDIM  2048
#define BDIM  2
#define NJ    4096            // BDIM*PDIM
#define MAXIT 100

// ---- k_iter0 geometry: 512 blocks x 512 threads, 4-way k-split ----
#define NBI   512
#define NTI   512
#define KSI   4               // k-splits
#define KGI   16              // k-groups per block
#define KPTI  10              // k per thread
// ---- k_rest geometry ----
#define NBLK  128
#define NTHR  256
#define JPB   32
#define KCH   8
#define KPT   80

// ws float offsets (no memset; header zeroed by k_iter0 blk0)
#define OFF_SLOT 0            // u64 slot[2][NBLK] = 512 floats
#define OFF_REL  512          // u64 release word (own cache line)
#define OFF_HDR  576          // header floats zeroed each launch
#define OFF_VKP  576          // 512 vk partials
#define OFF_CVP  1088         // 512 cv partials
#define OFF_U2   1600         // 4 x 40960 per-ks u partials
#define OFF_XB   165440       // 2621440 x ping-pong partner of d_out
#define WS_FLOATS (OFF_XB + BDIM*KDIM*PDIM)   // 11.15 MB

#define SEQ(wv)   ((int)(((wv) >> 3) & 0x1FFFFFFF))
#define FLUSH(wv) ((int)(((wv) >> 2) & 1))
#define DONE(wv)  ((int)((wv) & 1))

__device__ __forceinline__ float sgnf(float x) {
  return (x > 0.f) ? 1.f : ((x < 0.f) ? -1.f : 0.f);
}
__device__ __forceinline__ float shrinkf(float v, float lam) {
  return (v > lam) ? v - lam : ((v < -lam) ? v + lam : 0.f);
}

// build normalized dictionary into LDS + L = ||DtD||_F via 10x10 DD^T identity
template <int NT>
__device__ void build_D_L(const float* __restrict__ Drr, const float* __restrict__ Dth,
                          float (*Dl)[TDIM], float* Msh, float& linv, float& lambd) {
  const int tid = threadIdx.x, w = tid >> 6, l = tid & 63;
  for (int k = tid; k < KDIM; k += NT) {
    int n = k % NPOLE, grp = k / NPOLE;
    float r = Drr[n], th = Dth[n];
    float col[TDIM]; float ss = 0.f, ri = 1.f;
    #pragma unroll
    for (int i = 0; i < TDIM; ++i) {
      float ang = (float)i * th;
      float c = __cosf(ang), s = __sinf(ang);
      float sgn = (i & 1) ? -1.f : 1.f;
      float v = (grp == 0) ? ri * c : (grp == 1) ? sgn * ri * c
               : (grp == 2) ? ri * s : sgn * ri * s;
      col[i] = v; ss += v * v; ri *= r;
    }
    float G = sqrtf(ss); if (G == 0.f) G = sqrtf((float)TDIM);
    float gi = 1.f / G;
    #pragma unroll
    for (int i = 0; i < TDIM; ++i) Dl[k][i] = col[i] * gi;
  }
  __syncthreads();
  const int NW = NT / 64;
  for (int e = w; e < 55; e += NW) {
    int cnt = e, t1 = 0, t2 = 0;
    for (int q = 0; q < TDIM; ++q) { int row = TDIM - q; if (cnt < row) { t1 = q; t2 = q + cnt; break; } cnt -= row; }
    float acc = 0.f;
    for (int k = l; k < KDIM; k += 64) acc += Dl[k][t1] * Dl[k][t2];
    #pragma unroll
    for (int o = 32; o > 0; o >>= 1) acc += __shfl_down(acc, o);
    if (l == 0) Msh[e] = acc;
  }
  __syncthreads();
  float fro = 0.f;
  {
    int e = 0;
    for (int t1 = 0; t1 < TDIM; ++t1)
      for (int t2 = t1; t2 < TDIM; ++t2, ++e) {
        float m = Msh[e];
        fro += (t1 == t2 ? 1.f : 2.f) * m * m;
      }
  }
  linv = 1.f / sqrtf(fro);
  lambd = 0.1f * linv;
}

// masked-dictionary alpha (block-uniform call; 4-wave blocks)
__device__ float alpha_eval(const float* __restrict__ xn, const float (*Dl)[TDIM],
                            float* csum, double (*Mm)[TDIM], float* bcf,
                            float linv, int w, int l, int tid) {
  for (int k = w; k < KDIM; k += 4) {
    float acc = 0.f;
    for (int idx = l; idx < NJ; idx += 64) {
      int b2 = idx >> 11, p2 = idx & (PDIM - 1);
      acc += xn[((b2 * KDIM + k) << 11) | p2];
    }
    #pragma unroll
    for (int o = 32; o > 0; o >>= 1) acc += __shfl_down(acc, o);
    if (l == 0) csum[k] = acc;
  }
  __syncthreads();
  float accE = 0.f;
  if (tid < 55) {
    int cnt = tid, ea = 0, eb = 0;
    for (int q = 0; q < TDIM; ++q) { int row = TDIM - q; if (cnt < row) { ea = q; eb = q + cnt; break; } cnt -= row; }
    for (int k = 0; k < KDIM; ++k) {
      float m = fabsf(csum[k] / (float)PDIM / (float)BDIM);
      if (m >= 1e-3f) accE += Dl[k][ea] * Dl[k][eb];
    }
  }
  if (w == 0) {
    for (int e2 = 0; e2 < 55; ++e2) {
      float vsh = __shfl(accE, e2);
      if (l == 0) {
        int cnt = e2, a2 = 0, b2 = 0;
        for (int q = 0; q < TDIM; ++q) { int row = TDIM - q; if (cnt < row) { a2 = q; b2 = q + cnt; break; } cnt -= row; }
        Mm[a2][b2] = (double)vsh; Mm[b2][a2] = (double)vsh;
      }
    }
  }
  __syncthreads();
  if (tid == 0) {
    for (int sw = 0; sw < 60; ++sw) {
      double off = 0.0;
      for (int a2 = 0; a2 < TDIM; ++a2)
        for (int b2 = a2 + 1; b2 < TDIM; ++b2) off += Mm[a2][b2] * Mm[a2][b2];
      if (off < 1e-22) break;
      for (int a2 = 0; a2 < TDIM - 1; ++a2)
        for (int b2 = a2 + 1; b2 < TDIM; ++b2) {
          double apq = Mm[a2][b2];
          if (fabs(apq) < 1e-30) continue;
          double app = Mm[a2][a2], aqq = Mm[b2][b2];
          double theta = (aqq - app) / (2.0 * apq);
          double tj = (theta >= 0.0 ? 1.0 : -1.0) / (fabs(theta) + sqrt(theta * theta + 1.0));
          double cj = 1.0 / sqrt(tj * tj + 1.0);
          double sj = tj * cj;
          for (int q2 = 0; q2 < TDIM; ++q2) {
            double ap = Mm[a2][q2], aq = Mm[b2][q2];
            Mm[a2][q2] = cj * ap - sj * aq;
            Mm[b2][q2] = sj * ap + cj * aq;
          }
          for (int q2 = 0; q2 < TDIM; ++q2) {
            double ap = Mm[q2][a2], aq = Mm[q2][b2];
            Mm[q2][a2] = cj * ap - sj * aq;
            Mm[q2][b2] = sj * ap + cj * aq;
          }
        }
    }
    float pmin = 3.4e38f; int found = 0;
    for (int a2 = 0; a2 < TDIM; ++a2) {
      float ev = (float)Mm[a2][a2];
      if (ev > 1e-4f) { if (ev < pmin) pmin = ev; found = 1; }
    }
    float pp = found ? pmin : 1.0f;
    float sq = sqrtf(linv * pp);
    bcf[0] = 4.0f * (1.0f - sq) * (1.0f - sq) / (1.0f - pp * linv);
  }
  __syncthreads();
  return bcf[0];
}

// ---------------- k_iter0: D+L build, iteration 0, partials, header zero ----
__global__ void __launch_bounds__(NTI)
k_iter0(const float* __restrict__ Y, const float* __restrict__ Drr,
        const float* __restrict__ Dth, float* __restrict__ ws,
        float* __restrict__ out) {
  const int tid = threadIdx.x, blk = blockIdx.x;
  const int w = tid >> 6, l = tid & 63;
  const int ks = blk >> 7, jt = blk & 127;
  const int jl = tid & 31, kg = tid >> 5;
  const int j = jt * JPB + jl, b = j >> 11, p = j & (PDIM - 1);
  const int k0 = ks * (KGI * KPTI) + kg * KPTI;

  __shared__ float Dl[KDIM][TDIM];        // 25.6 KB
  __shared__ float znL[KGI][TDIM][JPB];   // 20.5 KB
  __shared__ float Msh[64];
  __shared__ float redc[8];

  if (blk == 0)   // zero sync header for k_rest (visible at dispatch boundary)
    for (int i = tid; i < OFF_HDR; i += NTI) ws[i] = 0.f;

  // hoist Y loads: HBM latency hides under the trig-heavy D-build
  float Yreg[TDIM];
  #pragma unroll
  for (int t = 0; t < TDIM; ++t) Yreg[t] = Y[(b * TDIM + t) * PDIM + p];

  float linv, lambd;
  build_D_L<NTI>(Drr, Dth, Dl, Msh, linv, lambd);

  float zn[TDIM];
  #pragma unroll
  for (int t = 0; t < TDIM; ++t) zn[t] = 0.f;
  float cv = 0.f;
  #pragma unroll
  for (int s = 0; s < KPTI; ++s) {
    int k = k0 + s;
    int addr = ((b * KDIM + k) << 11) | p;
    float dt = 0.f;
    #pragma unroll
    for (int t = 0; t < TDIM; ++t) dt += Dl[k][t] * Yreg[t];
    float xv = shrinkf(linv * dt, lambd);
    out[addr] = xv;
    #pragma unroll
    for (int t = 0; t < TDIM; ++t) zn[t] += Dl[k][t] * xv;
    cv += xv * xv;
  }
  #pragma unroll
  for (int t = 0; t < TDIM; ++t) znL[kg][t][jl] = zn[t];
  __syncthreads();
  if (tid < TDIM * JPB) {                  // u partials for this (ks, jt)
    int t = tid >> 5, j2 = tid & 31;
    float s = 0.f;
    #pragma unroll
    for (int g = 0; g < KGI; ++g) s += znL[g][t][j2];
    ws[OFF_U2 + ks * (TDIM * NJ) + t * NJ + jt * JPB + j2] = s;
  }
  // cv reduce: wave shuffle + 8-leader LDS
  #pragma unroll
  for (int o = 32; o > 0; o >>= 1) cv += __shfl_down(cv, o);
  if (l == 0) redc[w] = cv;
  __syncthreads();
  if (tid == 0) {
    float s = 0.f;
    #pragma unroll
    for (int q = 0; q < 8; ++q) s += redc[q];
    ws[OFF_VKP + blk] = -s;                // vk(ii=0) = -||x1||^2 exactly
    ws[OFF_CVP + blk] = s;
  }
}

// ---------------- k_rest: redundant entry control; loop only if needed ------
__global__ void __launch_bounds__(NTHR)
k_rest(const float* __restrict__ Y, const float* __restrict__ Drr,
       const float* __restrict__ Dth, float* __restrict__ ws,
       float* __restrict__ out) {
  const int tid = threadIdx.x, blk = blockIdx.x;
  const int w = tid >> 6, l = tid & 63;
  const int jl = tid & 31, kc = tid >> 5;
  const int j = blk * JPB + jl;
  const int b = j >> 11, p = j & (PDIM - 1);
  const int k0 = kc * KPT;
  unsigned long long* slot = (unsigned long long*)(ws + OFF_SLOT);
  unsigned long long* rel  = (unsigned long long*)(ws + OFF_REL);

  __shared__ float red[NTHR], red2[NTHR];

  // ---- entry: every block redundantly reduces the 512 partials ----
  red[tid]  = ws[OFF_VKP + tid] + ws[OFF_VKP + tid + NTHR];
  red2[tid] = ws[OFF_CVP + tid] + ws[OFF_CVP + tid + NTHR];
  __syncthreads();
  for (int o = NTHR >> 1; o > 0; o >>= 1) {
    if (tid < o) { red[tid] += red[tid + o]; red2[tid] += red2[tid + o]; }
    __syncthreads();
  }
  const float vkt0 = red[0], cvt0 = red2[0];
  if (sqrtf(cvt0) / (float)PDIM < 0.01f) return;   // converged at ii=0 (common)

  // ---- not converged: full state + loop ----
  __shared__ float Dl[KDIM][TDIM];
  __shared__ float znL[KCH][TDIM][JPB];
  __shared__ float uL[2][TDIM][JPB];
  __shared__ float csum[KDIM];
  __shared__ float Msh[64];
  __shared__ double Mm[TDIM][TDIM];
  __shared__ float vkbufL[MAXIT];
  __shared__ float bcf[4];

  float linv, lambd;
  build_D_L<NTHR>(Drr, Dth, Dl, Msh, linv, lambd);

  float Yreg[TDIM];
  #pragma unroll
  for (int t = 0; t < TDIM; ++t) Yreg[t] = Y[(b * TDIM + t) * PDIM + p];
  for (int i = tid; i < TDIM * JPB; i += NTHR) {
    int t = i >> 5, j2 = i & 31;
    float s = 0.f;
    #pragma unroll
    for (int q = 0; q < KSI; ++q)
      s += ws[OFF_U2 + q * (TDIM * NJ) + t * NJ + blk * JPB + j2];
    uL[0][t][j2] = s;
  }
  if (tid == 0) vkbufL[0] = vkt0;
  __syncthreads();

  // entry control for ii = 0 (redundant per block, bit-identical)
  float st_t, st_r, tt;
  int oscF, oscS, kpos, gap_ = 0;
  {
    int cond1 = (vkt0 >= 0.f);
    float r_alpha = 0.f;
    if (cond1) r_alpha = alpha_eval(out, Dl, csum, Mm, bcf, linv, w, l, tid);
    float r1 = (r_alpha == 4.0f) ? 3.99f : r_alpha;
    float r_new = cond1 ? r1 : 4.f;
    float t_cur = cond1 ? (4.0f / (4.0f - r1) / 1.1f) : 1.f;
    kpos = cond1 ? 10 : 0;
    oscF = !cond1;
    oscS = cond1 ? 1 : 0;
    float t_next = (1.f + sqrtf(1.f + r_new * t_cur * t_cur)) * 0.5f;
    tt = (t_cur - 1.f) / t_next;
    st_t = t_next; st_r = r_new;
  }

  float* wsX = ws + OFF_XB;
  int relcnt = 0, lastii = MAXIT - 1;

  for (int ii = 1; ii < MAXIT; ++ii) {
    const int pz = (ii <= 1);
    const int pr = ii & 1;
    float*       xnw  = pr ? wsX : out;
    const float* xcur = pr ? out : wsX;
    const float om = 1.f + tt;

    float zj[TDIM];
    #pragma unroll
    for (int t = 0; t < TDIM; ++t) {
      float a  = uL[pr ^ 1][t][jl];
      float bb = pz ? 0.f : uL[pr][t][jl];
      zj[t] = om * a - tt * bb;
    }
    float zn[TDIM];
    #pragma unroll
    for (int t = 0; t < TDIM; ++t) zn[t] = 0.f;
    float vk = 0.f, cv = 0.f;

    for (int s = 0; s < KPT; ++s) {
      int k = k0 + s;
      int addr = ((b * KDIM + k) << 11) | p;
      float xcv = xcur[addr];
      float xov = pz ? 0.f : xnw[addr];
      float y   = om * xcv - tt * xov;
      float wd = 0.f, dt = 0.f;
      #pragma unroll
      for (int t = 0; t < TDIM; ++t) { wd += Dl[k][t] * zj[t]; dt += Dl[k][t] * Yreg[t]; }
      float v = y + linv * (dt - wd);
      float xv = shrinkf(v, lambd);
      xnw[addr] = xv;
      #pragma unroll
      for (int t = 0; t < TDIM; ++t) zn[t] += Dl[k][t] * xv;
      vk += (y - xv) * (xv - xcv);
      float d = xv - xcv; cv += d * d;
    }

    #pragma unroll
    for (int t = 0; t < TDIM; ++t) znL[kc][t][jl] = zn[t];
    red[tid] = vk; red2[tid] = cv;
    __syncthreads();
    for (int i = tid; i < TDIM * JPB; i += NTHR) {
      int t = i >> 5, j2 = i & 31;
      float s = 0.f;
      #pragma unroll
      for (int c = 0; c < KCH; ++c) s += znL[c][t][j2];
      uL[pr][t][j2] = s;
    }
    for (int o = NTHR >> 1; o > 0; o >>= 1) {
      if (tid < o) { red[tid] += red[tid + o]; red2[tid] += red2[tid + o]; }
      __syncthreads();
    }
    if (tid == 0) {
      unsigned long long pay =
          ((unsigned long long)__float_as_uint(red2[0] + 1.0f) << 32)
        | (unsigned long long)__float_as_uint(red[0]);
      __hip_atomic_store(&slot[pr * NBLK + blk], pay, __ATOMIC_RELAXED, __HIP_MEMORY_SCOPE_AGENT);
    }

    if (blk == 0) {
      float pvk = 0.f, pcv = 0.f;
      if (tid < NBLK) {
        unsigned long long v; int g = 0;
        for (;;) {
          v = __hip_atomic_load(&slot[pr * NBLK + tid], __ATOMIC_RELAXED, __HIP_MEMORY_SCOPE_AGENT);
          if ((unsigned)(v >> 32) != 0u) break;
          __builtin_amdgcn_s_sleep(4);
          if (++g > (1 << 22)) break;
        }
        pvk = __uint_as_float((unsigned)v);
        pcv = __uint_as_float((unsigned)(v >> 32)) - 1.0f;
        __hip_atomic_store(&slot[pr * NBLK + tid], 0ULL, __ATOMIC_RELAXED, __HIP_MEMORY_SCOPE_AGENT);
      }
      red[tid] = pvk; red2[tid] = pcv;
      __syncthreads();
      for (int o = NTHR >> 1; o > 0; o >>= 1) {
        if (tid < o) { red[tid] += red[tid + o]; red2[tid] += red2[tid + o]; }
        __syncthreads();
      }
      float vkt = red[0], cvt = red2[0];
      if (tid == 0) vkbufL[ii] = vkt;
      __syncthreads();

      int cond1 = oscF && (vkt >= 0.f);
      int Lg = ii - kpos;
      float sum_k = 0.f;
      if (Lg >= 3) {
        int i1 = ii - 1;   i1 = i1 < 0 ? 0 : (i1 > MAXIT - 1 ? MAXIT - 1 : i1);
        int i2 = kpos + 1; i2 = i2 < 0 ? 0 : (i2 > MAXIT - 1 ? MAXIT - 1 : i2);
        sum_k = sgnf(vkbufL[i1]) - sgnf(vkbufL[i2]);
      }
      int cond2 = oscS && (vkt <= 0.f) && (Lg >= 2 * gap_) && (sum_k == 0.f);

      float r_alpha = 0.f;
      if (cond1 || cond2) {
        ++relcnt;      // flush protocol for cross-block x visibility
        if (tid == 0) {
          unsigned long long wv = ((unsigned long long)(unsigned)relcnt << 3) | 4ULL;
          __hip_atomic_store(rel, wv, __ATOMIC_RELEASE, __HIP_MEMORY_SCOPE_AGENT);
          __hip_atomic_store(&slot[(pr ^ 1) * NBLK + 0], 1ULL << 32, __ATOMIC_RELAXED, __HIP_MEMORY_SCOPE_AGENT);
        }
        if (tid < NBLK) {
          int g = 0;
          while ((unsigned)(__hip_atomic_load(&slot[(pr ^ 1) * NBLK + tid], __ATOMIC_RELAXED,
                                              __HIP_MEMORY_SCOPE_AGENT) >> 32) == 0u) {
            __builtin_amdgcn_s_sleep(4);
            if (++g > (1 << 22)) break;
          }
        }
        __syncthreads();
        if (tid == 0) __threadfence();
        __syncthreads();
        if (tid < NBLK)
          __hip_atomic_store(&slot[(pr ^ 1) * NBLK + tid], 0ULL, __ATOMIC_RELAXED, __HIP_MEMORY_SCOPE_AGENT);
        r_alpha = alpha_eval(pr ? wsX : out, Dl, csum, Mm, bcf, linv, w, l, tid);
      }

      float r1 = (r_alpha == 4.0f) ? 3.99f : r_alpha;
      float r_new = cond1 ? r1 : (cond2 ? r_alpha : st_r);
      float t_cur = cond1 ? (4.0f / (4.0f - r1) / 1.1f) : st_t;
      kpos = cond1 ? (ii + 10) : kpos;
      gap_ = cond1 ? ii : gap_;
      oscF = oscF && !cond1;
      oscS = cond1 ? 1 : (oscS && !cond2);
      float t_next = (1.f + sqrtf(1.f + r_new * t_cur * t_cur)) * 0.5f;
      float tt_new = (t_cur - 1.f) / t_next;
      float conv = sqrtf(cvt) / (float)KDIM;
      st_t = t_next; st_r = r_new;
      int done = (conv < 0.01f) ? 1 : 0;
      ++relcnt;
      if (tid == 0) {
        unsigned long long wv =
            ((unsigned long long)__float_as_uint(tt_new) << 32)
          | ((unsigned long long)(unsigned)relcnt << 3) | (unsigned long long)done;
        __hip_atomic_store(rel, wv, __ATOMIC_RELEASE, __HIP_MEMORY_SCOPE_AGENT);
      }
      tt = tt_new;
      if (done) { lastii = ii; break; }
    } else {
      if (tid == 0) {
        int exps = relcnt + 1;
        for (;;) {
          unsigned long long wv; int g = 0;
          for (;;) {
            wv = __hip_atomic_load(rel, __ATOMIC_RELAXED, __HIP_MEMORY_SCOPE_AGENT);
            if (SEQ(wv) >= exps) break;
            __builtin_amdgcn_s_sleep(4);
            if (++g > (1 << 22)) break;
          }
          if (FLUSH(wv) && SEQ(wv) == exps) {
            __threadfence();
            __hip_atomic_store(&slot[(pr ^ 1) * NBLK + blk], 1ULL << 32,
                               __ATOMIC_RELAXED, __HIP_MEMORY_SCOPE_AGENT);
            ++exps;
            continue;
          }
          relcnt = exps;
          bcf[0] = __uint_as_float((unsigned)(wv >> 32));
          bcf[1] = (float)DONE(wv);
          break;
        }
      }
      __syncthreads();
      tt = bcf[0];
      float dn = bcf[1];
      __syncthreads();
      if (dn != 0.f) { lastii = ii; break; }
    }
  }

  // final x parity: odd lastii -> copy own region wsX -> out
  if (lastii & 1) {
    for (int s = 0; s < KPT; ++s) {
      int k = k0 + s;
      int addr = ((b * KDIM + k) << 11) | p;
      out[addr] = wsX[addr];
    }
  }
}

extern "C" void kernel_launch(void* const* d_in, const int* in_sizes, int n_in,
                              void* d_out, int out_size, void* d_ws, size_t ws_size,
                              hipStream_t stream) {
  (void)in_sizes; (void)n_in; (void)out_size;
  if (ws_size < (size_t)WS_FLOATS * 4) return;
  const float* Y   = (const float*)d_in[0];
  const float* Drr = (const float*)d_in[1];
  const float* Dth = (const float*)d_in[2];
  float* out = (float*)d_out;
  float* ws  = (float*)d_ws;

  hipLaunchKernelGGL(k_iter0, dim3(NBI), dim3(NTI), 0, stream, Y, Drr, Dth, ws, out);
  hipLaunchKernelGGL(k_rest, dim3(NBLK), dim3(NTHR), 0, stream, Y, Drr, Dth, ws, out);
}

// Round 10
// 20.564 us; speedup vs baseline: 10.5366x; 1.0465x over previous
//
#include <hip/hip_runtime.h>

#define NPOLE 160
#define KDIM  640
#define TDIM  10
#define PDIM  2048
#define BDIM  2
#define NJ    4096            // BDIM*PDIM
#define MAXIT 100

// ---- k_iter0 geometry: 512 blocks x 512 threads, 4-way k-split ----
#define NBI   512
#define NTI   512
#define KGI   16              // k-groups per block
#define KPTI  10              // k per thread
// ---- k_rest geometry ----
#define NBLK  128
#define NTHR  256
#define JPB   32
#define KCH   8
#define KPT   80

// ws float offsets (no memset; header zeroed by k_iter0 blk0)
#define OFF_SLOT 0            // u64 slot[2][NBLK] = 512 floats
#define OFF_REL  512          // u64 release word (own cache line)
#define OFF_HDR  576          // header floats zeroed each launch
#define OFF_VKP  576          // 512 vk partials
#define OFF_CVP  1088         // 512 cv partials
#define OFF_XB   1600         // 2621440 x ping-pong partner of d_out
#define WS_FLOATS (OFF_XB + BDIM*KDIM*PDIM)   // 10.49 MB

#define SEQ(wv)   ((int)(((wv) >> 3) & 0x1FFFFFFF))
#define FLUSH(wv) ((int)(((wv) >> 2) & 1))
#define DONE(wv)  ((int)((wv) & 1))

__device__ __forceinline__ float sgnf(float x) {
  return (x > 0.f) ? 1.f : ((x < 0.f) ? -1.f : 0.f);
}
__device__ __forceinline__ float shrinkf(float v, float lam) {
  return (v > lam) ? v - lam : ((v < -lam) ? v + lam : 0.f);
}

// build normalized dictionary into LDS + L = ||DtD||_F via 10x10 DD^T identity
template <int NT>
__device__ void build_D_L(const float* __restrict__ Drr, const float* __restrict__ Dth,
                          float (*Dl)[TDIM], float* Msh, float& linv, float& lambd) {
  const int tid = threadIdx.x, w = tid >> 6, l = tid & 63;
  for (int k = tid; k < KDIM; k += NT) {
    int n = k % NPOLE, grp = k / NPOLE;
    float r = Drr[n], th = Dth[n];
    float col[TDIM]; float ss = 0.f, ri = 1.f;
    #pragma unroll
    for (int i = 0; i < TDIM; ++i) {
      float ang = (float)i * th;
      float c = __cosf(ang), s = __sinf(ang);
      float sgn = (i & 1) ? -1.f : 1.f;
      float v = (grp == 0) ? ri * c : (grp == 1) ? sgn * ri * c
               : (grp == 2) ? ri * s : sgn * ri * s;
      col[i] = v; ss += v * v; ri *= r;
    }
    float G = sqrtf(ss); if (G == 0.f) G = sqrtf((float)TDIM);
    float gi = 1.f / G;
    #pragma unroll
    for (int i = 0; i < TDIM; ++i) Dl[k][i] = col[i] * gi;
  }
  __syncthreads();
  const int NW = NT / 64;
  for (int e = w; e < 55; e += NW) {
    int cnt = e, t1 = 0, t2 = 0;
    for (int q = 0; q < TDIM; ++q) { int row = TDIM - q; if (cnt < row) { t1 = q; t2 = q + cnt; break; } cnt -= row; }
    float acc = 0.f;
    for (int k = l; k < KDIM; k += 64) acc += Dl[k][t1] * Dl[k][t2];
    #pragma unroll
    for (int o = 32; o > 0; o >>= 1) acc += __shfl_down(acc, o);
    if (l == 0) Msh[e] = acc;
  }
  __syncthreads();
  float fro = 0.f;
  {
    int e = 0;
    for (int t1 = 0; t1 < TDIM; ++t1)
      for (int t2 = t1; t2 < TDIM; ++t2, ++e) {
        float m = Msh[e];
        fro += (t1 == t2 ? 1.f : 2.f) * m * m;
      }
  }
  linv = 1.f / sqrtf(fro);
  lambd = 0.1f * linv;
}

// masked-dictionary alpha (block-uniform call; 4-wave blocks)
__device__ float alpha_eval(const float* __restrict__ xn, const float (*Dl)[TDIM],
                            float* csum, double (*Mm)[TDIM], float* bcf,
                            float linv, int w, int l, int tid) {
  for (int k = w; k < KDIM; k += 4) {
    float acc = 0.f;
    for (int idx = l; idx < NJ; idx += 64) {
      int b2 = idx >> 11, p2 = idx & (PDIM - 1);
      acc += xn[((b2 * KDIM + k) << 11) | p2];
    }
    #pragma unroll
    for (int o = 32; o > 0; o >>= 1) acc += __shfl_down(acc, o);
    if (l == 0) csum[k] = acc;
  }
  __syncthreads();
  float accE = 0.f;
  if (tid < 55) {
    int cnt = tid, ea = 0, eb = 0;
    for (int q = 0; q < TDIM; ++q) { int row = TDIM - q; if (cnt < row) { ea = q; eb = q + cnt; break; } cnt -= row; }
    for (int k = 0; k < KDIM; ++k) {
      float m = fabsf(csum[k] / (float)PDIM / (float)BDIM);
      if (m >= 1e-3f) accE += Dl[k][ea] * Dl[k][eb];
    }
  }
  if (w == 0) {
    for (int e2 = 0; e2 < 55; ++e2) {
      float vsh = __shfl(accE, e2);
      if (l == 0) {
        int cnt = e2, a2 = 0, b2 = 0;
        for (int q = 0; q < TDIM; ++q) { int row = TDIM - q; if (cnt < row) { a2 = q; b2 = q + cnt; break; } cnt -= row; }
        Mm[a2][b2] = (double)vsh; Mm[b2][a2] = (double)vsh;
      }
    }
  }
  __syncthreads();
  if (tid == 0) {
    for (int sw = 0; sw < 60; ++sw) {
      double off = 0.0;
      for (int a2 = 0; a2 < TDIM; ++a2)
        for (int b2 = a2 + 1; b2 < TDIM; ++b2) off += Mm[a2][b2] * Mm[a2][b2];
      if (off < 1e-22) break;
      for (int a2 = 0; a2 < TDIM - 1; ++a2)
        for (int b2 = a2 + 1; b2 < TDIM; ++b2) {
          double apq = Mm[a2][b2];
          if (fabs(apq) < 1e-30) continue;
          double app = Mm[a2][a2], aqq = Mm[b2][b2];
          double theta = (aqq - app) / (2.0 * apq);
          double tj = (theta >= 0.0 ? 1.0 : -1.0) / (fabs(theta) + sqrt(theta * theta + 1.0));
          double cj = 1.0 / sqrt(tj * tj + 1.0);
          double sj = tj * cj;
          for (int q2 = 0; q2 < TDIM; ++q2) {
            double ap = Mm[a2][q2], aq = Mm[b2][q2];
            Mm[a2][q2] = cj * ap - sj * aq;
            Mm[b2][q2] = sj * ap + cj * aq;
          }
          for (int q2 = 0; q2 < TDIM; ++q2) {
            double ap = Mm[q2][a2], aq = Mm[q2][b2];
            Mm[q2][a2] = cj * ap - sj * aq;
            Mm[q2][b2] = sj * ap + cj * aq;
          }
        }
    }
    float pmin = 3.4e38f; int found = 0;
    for (int a2 = 0; a2 < TDIM; ++a2) {
      float ev = (float)Mm[a2][a2];
      if (ev > 1e-4f) { if (ev < pmin) pmin = ev; found = 1; }
    }
    float pp = found ? pmin : 1.0f;
    float sq = sqrtf(linv * pp);
    bcf[0] = 4.0f * (1.0f - sq) * (1.0f - sq) / (1.0f - pp * linv);
  }
  __syncthreads();
  return bcf[0];
}

// ------ k_iter0: D+L build, iteration-0 x-write, cv partials, header zero ---
__global__ void __launch_bounds__(NTI)
k_iter0(const float* __restrict__ Y, const float* __restrict__ Drr,
        const float* __restrict__ Dth, float* __restrict__ ws,
        float* __restrict__ out) {
  const int tid = threadIdx.x, blk = blockIdx.x;
  const int w = tid >> 6, l = tid & 63;
  const int ks = blk >> 7, jt = blk & 127;
  const int jl = tid & 31, kg = tid >> 5;
  const int j = jt * JPB + jl, b = j >> 11, p = j & (PDIM - 1);
  const int k0 = ks * (KGI * KPTI) + kg * KPTI;

  __shared__ float Dl[KDIM][TDIM];        // 25.6 KB
  __shared__ float Msh[64];
  __shared__ float redc[8];

  if (blk == 0)   // zero sync header for k_rest (visible at dispatch boundary)
    for (int i = tid; i < OFF_HDR; i += NTI) ws[i] = 0.f;

  // hoist Y loads: HBM latency hides under the trig-heavy D-build
  float Yreg[TDIM];
  #pragma unroll
  for (int t = 0; t < TDIM; ++t) Yreg[t] = Y[(b * TDIM + t) * PDIM + p];

  float linv, lambd;
  build_D_L<NTI>(Drr, Dth, Dl, Msh, linv, lambd);

  float cv = 0.f;
  #pragma unroll
  for (int s = 0; s < KPTI; ++s) {
    int k = k0 + s;
    int addr = ((b * KDIM + k) << 11) | p;
    float dt = 0.f;
    #pragma unroll
    for (int t = 0; t < TDIM; ++t) dt += Dl[k][t] * Yreg[t];
    float xv = shrinkf(linv * dt, lambd);
    out[addr] = xv;
    cv += xv * xv;
  }
  // cv reduce: wave shuffle + 8-leader LDS
  #pragma unroll
  for (int o = 32; o > 0; o >>= 1) cv += __shfl_down(cv, o);
  if (l == 0) redc[w] = cv;
  __syncthreads();
  if (tid == 0) {
    float s = 0.f;
    #pragma unroll
    for (int q = 0; q < 8; ++q) s += redc[q];
    ws[OFF_VKP + blk] = -s;                // vk(ii=0) = -||x1||^2 exactly
    ws[OFF_CVP + blk] = s;
  }
}

// ---------------- k_rest: redundant entry control; loop only if needed ------
__global__ void __launch_bounds__(NTHR)
k_rest(const float* __restrict__ Y, const float* __restrict__ Drr,
       const float* __restrict__ Dth, float* __restrict__ ws,
       float* __restrict__ out) {
  const int tid = threadIdx.x, blk = blockIdx.x;
  const int w = tid >> 6, l = tid & 63;
  const int jl = tid & 31, kc = tid >> 5;
  const int j = blk * JPB + jl;
  const int b = j >> 11, p = j & (PDIM - 1);
  const int k0 = kc * KPT;
  unsigned long long* slot = (unsigned long long*)(ws + OFF_SLOT);
  unsigned long long* rel  = (unsigned long long*)(ws + OFF_REL);

  __shared__ float redw[8];

  // ---- entry: every block redundantly reduces the 512 partials (shuffle) ----
  float pv = ws[OFF_VKP + tid] + ws[OFF_VKP + tid + NTHR];
  float pc = ws[OFF_CVP + tid] + ws[OFF_CVP + tid + NTHR];
  #pragma unroll
  for (int o = 32; o > 0; o >>= 1) { pv += __shfl_down(pv, o); pc += __shfl_down(pc, o); }
  if (l == 0) { redw[w] = pv; redw[4 + w] = pc; }
  __syncthreads();
  const float vkt0 = redw[0] + redw[1] + redw[2] + redw[3];
  const float cvt0 = redw[4] + redw[5] + redw[6] + redw[7];
  if (sqrtf(cvt0) / (float)PDIM < 0.01f) return;   // converged at ii=0 (common)

  // ---- not converged: full state + loop ----
  __shared__ float Dl[KDIM][TDIM];
  __shared__ float znL[KCH][TDIM][JPB];
  __shared__ float uL[2][TDIM][JPB];
  __shared__ float red[NTHR], red2[NTHR];
  __shared__ float csum[KDIM];
  __shared__ float Msh[64];
  __shared__ double Mm[TDIM][TDIM];
  __shared__ float vkbufL[MAXIT];
  __shared__ float bcf[4];

  float linv, lambd;
  build_D_L<NTHR>(Drr, Dth, Dl, Msh, linv, lambd);

  float Yreg[TDIM];
  #pragma unroll
  for (int t = 0; t < TDIM; ++t) Yreg[t] = Y[(b * TDIM + t) * PDIM + p];

  // recompute uL[0] = D @ x1 for own j's from out (x1)
  {
    float zn[TDIM];
    #pragma unroll
    for (int t = 0; t < TDIM; ++t) zn[t] = 0.f;
    for (int s = 0; s < KPT; ++s) {
      int k = k0 + s;
      float xv = out[((b * KDIM + k) << 11) | p];
      #pragma unroll
      for (int t = 0; t < TDIM; ++t) zn[t] += Dl[k][t] * xv;
    }
    #pragma unroll
    for (int t = 0; t < TDIM; ++t) znL[kc][t][jl] = zn[t];
    __syncthreads();
    for (int i = tid; i < TDIM * JPB; i += NTHR) {
      int t = i >> 5, j2 = i & 31;
      float s = 0.f;
      #pragma unroll
      for (int c = 0; c < KCH; ++c) s += znL[c][t][j2];
      uL[0][t][j2] = s;
    }
  }
  if (tid == 0) vkbufL[0] = vkt0;
  __syncthreads();

  // entry control for ii = 0 (redundant per block, bit-identical)
  float st_t, st_r, tt;
  int oscF, oscS, kpos, gap_ = 0;
  {
    int cond1 = (vkt0 >= 0.f);
    float r_alpha = 0.f;
    if (cond1) r_alpha = alpha_eval(out, Dl, csum, Mm, bcf, linv, w, l, tid);
    float r1 = (r_alpha == 4.0f) ? 3.99f : r_alpha;
    float r_new = cond1 ? r1 : 4.f;
    float t_cur = cond1 ? (4.0f / (4.0f - r1) / 1.1f) : 1.f;
    kpos = cond1 ? 10 : 0;
    oscF = !cond1;
    oscS = cond1 ? 1 : 0;
    float t_next = (1.f + sqrtf(1.f + r_new * t_cur * t_cur)) * 0.5f;
    tt = (t_cur - 1.f) / t_next;
    st_t = t_next; st_r = r_new;
  }

  float* wsX = ws + OFF_XB;
  int relcnt = 0, lastii = MAXIT - 1;

  for (int ii = 1; ii < MAXIT; ++ii) {
    const int pz = (ii <= 1);
    const int pr = ii & 1;
    float*       xnw  = pr ? wsX : out;
    const float* xcur = pr ? out : wsX;
    const float om = 1.f + tt;

    float zj[TDIM];
    #pragma unroll
    for (int t = 0; t < TDIM; ++t) {
      float a  = uL[pr ^ 1][t][jl];
      float bb = pz ? 0.f : uL[pr][t][jl];
      zj[t] = om * a - tt * bb;
    }
    float zn[TDIM];
    #pragma unroll
    for (int t = 0; t < TDIM; ++t) zn[t] = 0.f;
    float vk = 0.f, cv = 0.f;

    for (int s = 0; s < KPT; ++s) {
      int k = k0 + s;
      int addr = ((b * KDIM + k) << 11) | p;
      float xcv = xcur[addr];
      float xov = pz ? 0.f : xnw[addr];
      float y   = om * xcv - tt * xov;
      float wd = 0.f, dt = 0.f;
      #pragma unroll
      for (int t = 0; t < TDIM; ++t) { wd += Dl[k][t] * zj[t]; dt += Dl[k][t] * Yreg[t]; }
      float v = y + linv * (dt - wd);
      float xv = shrinkf(v, lambd);
      xnw[addr] = xv;
      #pragma unroll
      for (int t = 0; t < TDIM; ++t) zn[t] += Dl[k][t] * xv;
      vk += (y - xv) * (xv - xcv);
      float d = xv - xcv; cv += d * d;
    }

    #pragma unroll
    for (int t = 0; t < TDIM; ++t) znL[kc][t][jl] = zn[t];
    red[tid] = vk; red2[tid] = cv;
    __syncthreads();
    for (int i = tid; i < TDIM * JPB; i += NTHR) {
      int t = i >> 5, j2 = i & 31;
      float s = 0.f;
      #pragma unroll
      for (int c = 0; c < KCH; ++c) s += znL[c][t][j2];
      uL[pr][t][j2] = s;
    }
    for (int o = NTHR >> 1; o > 0; o >>= 1) {
      if (tid < o) { red[tid] += red[tid + o]; red2[tid] += red2[tid + o]; }
      __syncthreads();
    }
    if (tid == 0) {
      unsigned long long pay =
          ((unsigned long long)__float_as_uint(red2[0] + 1.0f) << 32)
        | (unsigned long long)__float_as_uint(red[0]);
      __hip_atomic_store(&slot[pr * NBLK + blk], pay, __ATOMIC_RELAXED, __HIP_MEMORY_SCOPE_AGENT);
    }

    if (blk == 0) {
      float pvk = 0.f, pcv = 0.f;
      if (tid < NBLK) {
        unsigned long long v; int g = 0;
        for (;;) {
          v = __hip_atomic_load(&slot[pr * NBLK + tid], __ATOMIC_RELAXED, __HIP_MEMORY_SCOPE_AGENT);
          if ((unsigned)(v >> 32) != 0u) break;
          __builtin_amdgcn_s_sleep(4);
          if (++g > (1 << 22)) break;
        }
        pvk = __uint_as_float((unsigned)v);
        pcv = __uint_as_float((unsigned)(v >> 32)) - 1.0f;
        __hip_atomic_store(&slot[pr * NBLK + tid], 0ULL, __ATOMIC_RELAXED, __HIP_MEMORY_SCOPE_AGENT);
      }
      red[tid] = pvk; red2[tid] = pcv;
      __syncthreads();
      for (int o = NTHR >> 1; o > 0; o >>= 1) {
        if (tid < o) { red[tid] += red[tid + o]; red2[tid] += red2[tid + o]; }
        __syncthreads();
      }
      float vkt = red[0], cvt = red2[0];
      if (tid == 0) vkbufL[ii] = vkt;
      __syncthreads();

      int cond1 = oscF && (vkt >= 0.f);
      int Lg = ii - kpos;
      float sum_k = 0.f;
      if (Lg >= 3) {
        int i1 = ii - 1;   i1 = i1 < 0 ? 0 : (i1 > MAXIT - 1 ? MAXIT - 1 : i1);
        int i2 = kpos + 1; i2 = i2 < 0 ? 0 : (i2 > MAXIT - 1 ? MAXIT - 1 : i2);
        sum_k = sgnf(vkbufL[i1]) - sgnf(vkbufL[i2]);
      }
      int cond2 = oscS && (vkt <= 0.f) && (Lg >= 2 * gap_) && (sum_k == 0.f);

      float r_alpha = 0.f;
      if (cond1 || cond2) {
        ++relcnt;      // flush protocol for cross-block x visibility
        if (tid == 0) {
          unsigned long long wv = ((unsigned long long)(unsigned)relcnt << 3) | 4ULL;
          __hip_atomic_store(rel, wv, __ATOMIC_RELEASE, __HIP_MEMORY_SCOPE_AGENT);
          __hip_atomic_store(&slot[(pr ^ 1) * NBLK + 0], 1ULL << 32, __ATOMIC_RELAXED, __HIP_MEMORY_SCOPE_AGENT);
        }
        if (tid < NBLK) {
          int g = 0;
          while ((unsigned)(__hip_atomic_load(&slot[(pr ^ 1) * NBLK + tid], __ATOMIC_RELAXED,
                                              __HIP_MEMORY_SCOPE_AGENT) >> 32) == 0u) {
            __builtin_amdgcn_s_sleep(4);
            if (++g > (1 << 22)) break;
          }
        }
        __syncthreads();
        if (tid == 0) __threadfence();
        __syncthreads();
        if (tid < NBLK)
          __hip_atomic_store(&slot[(pr ^ 1) * NBLK + tid], 0ULL, __ATOMIC_RELAXED, __HIP_MEMORY_SCOPE_AGENT);
        r_alpha = alpha_eval(pr ? wsX : out, Dl, csum, Mm, bcf, linv, w, l, tid);
      }

      float r1 = (r_alpha == 4.0f) ? 3.99f : r_alpha;
      float r_new = cond1 ? r1 : (cond2 ? r_alpha : st_r);
      float t_cur = cond1 ? (4.0f / (4.0f - r1) / 1.1f) : st_t;
      kpos = cond1 ? (ii + 10) : kpos;
      gap_ = cond1 ? ii : gap_;
      oscF = oscF && !cond1;
      oscS = cond1 ? 1 : (oscS && !cond2);
      float t_next = (1.f + sqrtf(1.f + r_new * t_cur * t_cur)) * 0.5f;
      float tt_new = (t_cur - 1.f) / t_next;
      float conv = sqrtf(cvt) / (float)KDIM;
      st_t = t_next; st_r = r_new;
      int done = (conv < 0.01f) ? 1 : 0;
      ++relcnt;
      if (tid == 0) {
        unsigned long long wv =
            ((unsigned long long)__float_as_uint(tt_new) << 32)
          | ((unsigned long long)(unsigned)relcnt << 3) | (unsigned long long)done;
        __hip_atomic_store(rel, wv, __ATOMIC_RELEASE, __HIP_MEMORY_SCOPE_AGENT);
      }
      tt = tt_new;
      if (done) { lastii = ii; break; }
    } else {
      if (tid == 0) {
        int exps = relcnt + 1;
        for (;;) {
          unsigned long long wv; int g = 0;
          for (;;) {
            wv = __hip_atomic_load(rel, __ATOMIC_RELAXED, __HIP_MEMORY_SCOPE_AGENT);
            if (SEQ(wv) >= exps) break;
            __builtin_amdgcn_s_sleep(4);
            if (++g > (1 << 22)) break;
          }
          if (FLUSH(wv) && SEQ(wv) == exps) {
            __threadfence();
            __hip_atomic_store(&slot[(pr ^ 1) * NBLK + blk], 1ULL << 32,
                               __ATOMIC_RELAXED, __HIP_MEMORY_SCOPE_AGENT);
            ++exps;
            continue;
          }
          relcnt = exps;
          bcf[0] = __uint_as_float((unsigned)(wv >> 32));
          bcf[1] = (float)DONE(wv);
          break;
        }
      }
      __syncthreads();
      tt = bcf[0];
      float dn = bcf[1];
      __syncthreads();
      if (dn != 0.f) { lastii = ii; break; }
    }
  }

  // final x parity: odd lastii -> copy own region wsX -> out
  if (lastii & 1) {
    for (int s = 0; s < KPT; ++s) {
      int k = k0 + s;
      int addr = ((b * KDIM + k) << 11) | p;
      out[addr] = wsX[addr];
    }
  }
}

extern "C" void kernel_launch(void* const* d_in, const int* in_sizes, int n_in,
                              void* d_out, int out_size, void* d_ws, size_t ws_size,
                              hipStream_t stream) {
  (void)in_sizes; (void)n_in; (void)out_size;
  if (ws_size < (size_t)WS_FLOATS * 4) return;
  const float* Y   = (const float*)d_in[0];
  const float* Drr = (const float*)d_in[1];
  const float* Dth = (const float*)d_in[2];
  float* out = (float*)d_out;
  float* ws  = (float*)d_ws;

  hipLaunchKernelGGL(k_iter0, dim3(NBI), dim3(NTI), 0, stream, Y, Drr, Dth, ws, out);
  hipLaunchKernelGGL(k_rest, dim3(NBLK), dim3(NTHR), 0, stream, Y, Drr, Dth, ws, out);
}